// Round 6
// baseline (311.478 us; speedup 1.0000x reference)
//
#include <hip/hip_runtime.h>
#include <math.h>

#define N_TL 131072
#define GRID 2048          // 64 TLs per block, single pass
#define BLK 256

typedef __attribute__((ext_vector_type(8))) short bfrag;
typedef __attribute__((ext_vector_type(4))) float f32x4;

// RNE bf16 (weights, staged once)
__device__ __forceinline__ unsigned short f2bf_rne(float x) {
  unsigned int u = __float_as_uint(x);
  return (unsigned short)((u + 0x7fffu + ((u >> 16) & 1u)) >> 16);
}
// cheap round-half-up pack of 2 floats -> bf16x2 (activations)
__device__ __forceinline__ unsigned int pack2(float a, float b) {
  return ((__float_as_uint(a) + 0x8000u) >> 16) |
         ((__float_as_uint(b) + 0x8000u) & 0xffff0000u);
}
__device__ __forceinline__ f32x4 mfma16(bfrag a, bfrag b, f32x4 c) {
  return __builtin_amdgcn_mfma_f32_16x16x32_bf16(a, b, c, 0, 0, 0);
}
__device__ __forceinline__ float dot4(float4 a, float4 b) {
  return a.x * b.x + a.y * b.y + a.z * b.z + a.w * b.w;
}

// Weight A-fragment (W^T): A[m=col0+(lane&15)][k=k0+quad*8+j] = W[k][col]*scale, 0 for k>=K.
__device__ __forceinline__ bfrag load_wfragT(const float* __restrict__ w, int ncols,
                                             int col0, int k0, int lane, int K, float scale) {
  const int mm = lane & 15, qq = lane >> 4;
  bfrag f;
  #pragma unroll
  for (int j = 0; j < 8; ++j) {
    const int k = k0 + qq * 8 + j;
    const float v = (k < K) ? w[(size_t)k * ncols + col0 + mm] * scale : 0.f;
    f[j] = (short)f2bf_rne(v);
  }
  return f;
}

// B-operand (activations) from row-major bf16 LDS
#define LDBACT(arr, stride, nt, kk) \
  (*reinterpret_cast<const bfrag*>(&(arr)[((nt) * 16 + m) * (stride) + (kk) * 32 + quad * 8]))

// LDS: ~70 KB -> 2 blocks/CU
struct alignas(16) SmemF {
  union {
    float qkvf[64 * 196];          // qkv f32 during A attention (50.2 KB)
    unsigned short h[64 * 136];    // layer1 out bf16 (dead before qkv write)
    unsigned short ph[64 * 136];   // B: pL1 out; head-L1 out (A-part dead)
  };
  unsigned short emb[64 * 72];     // emb; om[16][264] overlays (9.2 KB)
  unsigned short xbuf[64 * 32];    // A layer1 input / B phase-L1 input (4 KB)
  unsigned short feat[64 * 200];   // [ctx(64) | phase_emb(128)] persists A->B (25.6 KB)
  float b1[128], b2[64], bin[192], bout[64];
  float pb1[128], pb2[128];
  float rbias[4][128];             // head_b1 + region[g] @ head_w1[192:200,:]
  float hw2[128];
  float consts[2];
  int ridx[64];
};

__global__ __launch_bounds__(BLK, 2)
void fused_policy(const float* __restrict__ queue,
                  const float* __restrict__ waiting,
                  const float* __restrict__ phase_onehot,
                  const float* __restrict__ elapsed,
                  const int* __restrict__ region_ids,
                  const float* __restrict__ noise,
                  const float* __restrict__ lane_w1,
                  const float* __restrict__ lane_b1,
                  const float* __restrict__ lane_w2,
                  const float* __restrict__ lane_b2,
                  const float* __restrict__ attn_in_w,
                  const float* __restrict__ attn_in_b,
                  const float* __restrict__ attn_out_w,
                  const float* __restrict__ attn_out_b,
                  const float* __restrict__ phase_w1,
                  const float* __restrict__ phase_b1,
                  const float* __restrict__ phase_w2,
                  const float* __restrict__ phase_b2,
                  const float* __restrict__ region_table,
                  const float* __restrict__ head_w1,
                  const float* __restrict__ head_b1,
                  const float* __restrict__ head_w2,
                  const float* __restrict__ head_b2,
                  const float* __restrict__ log_std,
                  float* __restrict__ out) {
  __shared__ SmemF S;
  const int tid  = threadIdx.x;
  const int wv   = tid >> 6;
  const int lane = tid & 63;
  const int m    = lane & 15;
  const int quad = lane >> 4;
  const int n0   = blockIdx.x * 64;         // 64 TLs per block
  const f32x4 Z = {0.f, 0.f, 0.f, 0.f};

  // ---- A-part register weight fragments (20 frags) ----
  bfrag wL1[2], wL2[4], wQKV[3][2], wOUT[8];
  #pragma unroll
  for (int Mi = 0; Mi < 2; ++Mi)
    wL1[Mi] = load_wfragT(lane_w1, 128, (wv * 2 + Mi) * 16, 0, lane, 3, 1.f);
  #pragma unroll
  for (int kk = 0; kk < 4; ++kk)
    wL2[kk] = load_wfragT(lane_w2, 64, wv * 16, kk * 32, lane, 128, 1.f);
  #pragma unroll
  for (int Mi = 0; Mi < 3; ++Mi)
    #pragma unroll
    for (int kk = 0; kk < 2; ++kk)
      wQKV[Mi][kk] = load_wfragT(attn_in_w, 192, (wv + Mi * 4) * 16, kk * 32, lane, 64,
                                 Mi == 0 ? 0.25f : 1.f);   // fold 1/sqrt(HD) into Q
  #pragma unroll
  for (int kk = 0; kk < 8; ++kk) {          // out-proj, query-mean folded (K=256)
    bfrag f;
    #pragma unroll
    for (int j = 0; j < 8; ++j) {
      const int k = kk * 32 + quad * 8 + j;
      f[j] = (short)f2bf_rne(attn_out_w[(size_t)(k & 63) * 64 + wv * 16 + m] * 0.25f);
    }
    wOUT[kk] = f;
  }
  // ---- B-part register weight fragments (22 frags): wave owns col tiles {2wv, 2wv+1} ----
  bfrag wP1[2], wP2[2][4], wH1[2][6];
  #pragma unroll
  for (int Mi = 0; Mi < 2; ++Mi) {
    wP1[Mi] = load_wfragT(phase_w1, 128, (wv * 2 + Mi) * 16, 0, lane, 5, 1.f);
    #pragma unroll
    for (int kk = 0; kk < 4; ++kk)
      wP2[Mi][kk] = load_wfragT(phase_w2, 128, (wv * 2 + Mi) * 16, kk * 32, lane, 128, 1.f);
    #pragma unroll
    for (int kk = 0; kk < 6; ++kk)
      wH1[Mi][kk] = load_wfragT(head_w1, 128, (wv * 2 + Mi) * 16, kk * 32, lane, 192, 1.f);
  }

  // ---- stage biases / constants ----
  for (int i = tid; i < 128; i += BLK) S.b1[i] = lane_b1[i];
  for (int i = tid; i < 64;  i += BLK) S.b2[i] = lane_b2[i];
  for (int i = tid; i < 192; i += BLK) S.bin[i] = attn_in_b[i] * ((i < 64) ? 0.25f : 1.f);
  for (int i = tid; i < 64;  i += BLK) S.bout[i] = attn_out_b[i];
  for (int i = tid; i < 128; i += BLK) S.pb1[i] = phase_b1[i];
  for (int i = tid; i < 128; i += BLK) S.pb2[i] = phase_b2[i];
  for (int i = tid; i < 128; i += BLK) S.hw2[i] = head_w2[i];
  for (int i = tid; i < 512; i += BLK) {
    const int g = i >> 7, c = i & 127;
    float acc = head_b1[c];
    #pragma unroll
    for (int j = 0; j < 8; ++j) acc += region_table[g * 8 + j] * head_w1[(192 + j) * 128 + c];
    S.rbias[g][c] = acc;
  }
  if (tid == 0) { S.consts[0] = head_b2[0]; S.consts[1] = log_std[0]; }
  if (tid < 64) {
    int r = region_ids[n0 + tid];
    S.ridx[tid] = r < 0 ? 0 : (r > 3 ? 3 : r);
  }
  // stage x for sub-iter 0 (16 TLs x 4 lane-rows, K padded to 32)
  {
    const int r = tid >> 2, seg = tid & 3;
    uint4 z = {0, 0, 0, 0};
    if (seg == 0) {
      const int gl = n0 * 4 + r;
      z.x = pack2(queue[gl], waiting[gl]);
      z.y = pack2(elapsed[n0 + (r >> 2)], 0.f);
    }
    *reinterpret_cast<uint4*>(&S.xbuf[r * 32 + seg * 8]) = z;
  }
  __syncthreads();

  // ================= A-part: 4 sub-iters of 16 TLs =================
  #pragma unroll 1
  for (int s = 0; s < 4; ++s) {
    const int tl0 = n0 + s * 16;

    // ---- layer1 MFMA (K=32 zero-padded): h^T = w1^T @ x ----
    {
      f32x4 acc[2][4];
      #pragma unroll
      for (int Mi = 0; Mi < 2; ++Mi)
        #pragma unroll
        for (int Nt = 0; Nt < 4; ++Nt) acc[Mi][Nt] = Z;
      #pragma unroll
      for (int Nt = 0; Nt < 4; ++Nt) {
        const bfrag b = LDBACT(S.xbuf, 32, Nt, 0);
        acc[0][Nt] = mfma16(wL1[0], b, acc[0][Nt]);
        acc[1][Nt] = mfma16(wL1[1], b, acc[1][Nt]);
      }
      #pragma unroll
      for (int Mi = 0; Mi < 2; ++Mi) {
        const int oc0 = (wv * 2 + Mi) * 16 + quad * 4;
        const f32x4 bb = *reinterpret_cast<const f32x4*>(&S.b1[oc0]);
        #pragma unroll
        for (int Nt = 0; Nt < 4; ++Nt) {
          const int row = Nt * 16 + m;
          uint2 u;
          u.x = pack2(fmaxf(acc[Mi][Nt][0] + bb[0], 0.f), fmaxf(acc[Mi][Nt][1] + bb[1], 0.f));
          u.y = pack2(fmaxf(acc[Mi][Nt][2] + bb[2], 0.f), fmaxf(acc[Mi][Nt][3] + bb[3], 0.f));
          *reinterpret_cast<uint2*>(&S.h[row * 136 + oc0]) = u;
        }
      }
    }
    __syncthreads();

    // ---- layer2: emb^T = w2^T @ h ----
    {
      f32x4 acc[4] = {Z, Z, Z, Z};
      #pragma unroll
      for (int Nt = 0; Nt < 4; ++Nt)
        #pragma unroll
        for (int kk = 0; kk < 4; ++kk)
          acc[Nt] = mfma16(wL2[kk], LDBACT(S.h, 136, Nt, kk), acc[Nt]);
      const int oc0 = wv * 16 + quad * 4;
      const f32x4 bb = *reinterpret_cast<const f32x4*>(&S.b2[oc0]);
      #pragma unroll
      for (int Nt = 0; Nt < 4; ++Nt) {
        const int row = Nt * 16 + m;
        uint2 u;
        u.x = pack2(fmaxf(acc[Nt][0] + bb[0], 0.f), fmaxf(acc[Nt][1] + bb[1], 0.f));
        u.y = pack2(fmaxf(acc[Nt][2] + bb[2], 0.f), fmaxf(acc[Nt][3] + bb[3], 0.f));
        *reinterpret_cast<uint2*>(&S.emb[row * 72 + oc0]) = u;
      }
    }
    __syncthreads();

    // ---- QKV: qkv^T = Win^T @ emb (f32 out); stage next x / B input ----
    {
      f32x4 acc[3][4];
      #pragma unroll
      for (int Mi = 0; Mi < 3; ++Mi)
        #pragma unroll
        for (int Nt = 0; Nt < 4; ++Nt) acc[Mi][Nt] = Z;
      #pragma unroll
      for (int Nt = 0; Nt < 4; ++Nt) {
        const bfrag e0 = LDBACT(S.emb, 72, Nt, 0);
        const bfrag e1 = LDBACT(S.emb, 72, Nt, 1);
        #pragma unroll
        for (int Mi = 0; Mi < 3; ++Mi) {
          acc[Mi][Nt] = mfma16(wQKV[Mi][0], e0, acc[Mi][Nt]);
          acc[Mi][Nt] = mfma16(wQKV[Mi][1], e1, acc[Mi][Nt]);
        }
      }
      #pragma unroll
      for (int Mi = 0; Mi < 3; ++Mi) {
        const int oc0 = (wv + Mi * 4) * 16 + quad * 4;
        const f32x4 bb = *reinterpret_cast<const f32x4*>(&S.bin[oc0]);
        #pragma unroll
        for (int Nt = 0; Nt < 4; ++Nt) {
          const int row = Nt * 16 + m;
          const f32x4 o = acc[Mi][Nt] + bb;
          *reinterpret_cast<f32x4*>(&S.qkvf[row * 196 + oc0]) = o;
        }
      }
      const int r = tid >> 2, seg = tid & 3;
      uint4 z = {0, 0, 0, 0};
      if (s < 3) {      // prefetch next sub-iter's lane inputs
        if (seg == 0) {
          const int gl = (tl0 + 16) * 4 + r;
          z.x = pack2(queue[gl], waiting[gl]);
          z.y = pack2(elapsed[tl0 + 16 + (r >> 2)], 0.f);
        }
      } else {          // stage B phase-L1 input (64 TLs, K padded to 32)
        if (seg == 0) {
          const float4 p = *reinterpret_cast<const float4*>(&phase_onehot[(n0 + r) * 4]);
          z.x = pack2(p.x, p.y);
          z.y = pack2(p.z, p.w);
          z.z = pack2(elapsed[n0 + r], 0.f);
        }
      }
      *reinterpret_cast<uint4*>(&S.xbuf[r * 32 + seg * 8]) = z;
    }
    __syncthreads();

    // ---- attention (f32 VALU): 16 threads/TL = 4 heads x 4 queries ----
    {
      const int tl = tid >> 4, l16 = tid & 15;
      const int hh = l16 >> 2, lq = l16 & 3;
      const float* qb = &S.qkvf[(tl * 4 + lq) * 196 + hh * 16];
      const float4 q0 = *reinterpret_cast<const float4*>(qb);
      const float4 q1 = *reinterpret_cast<const float4*>(qb + 4);
      const float4 q2 = *reinterpret_cast<const float4*>(qb + 8);
      const float4 q3 = *reinterpret_cast<const float4*>(qb + 12);
      float sc[4];
      #pragma unroll
      for (int lk = 0; lk < 4; ++lk) {
        const float* kb = &S.qkvf[(tl * 4 + lk) * 196 + 64 + hh * 16];
        sc[lk] = dot4(q0, *reinterpret_cast<const float4*>(kb))
               + dot4(q1, *reinterpret_cast<const float4*>(kb + 4))
               + dot4(q2, *reinterpret_cast<const float4*>(kb + 8))
               + dot4(q3, *reinterpret_cast<const float4*>(kb + 12));
      }
      const float mx = fmaxf(fmaxf(sc[0], sc[1]), fmaxf(sc[2], sc[3]));
      const float e0 = __expf(sc[0] - mx), e1 = __expf(sc[1] - mx);
      const float e2 = __expf(sc[2] - mx), e3 = __expf(sc[3] - mx);
      const float inv = 1.f / (e0 + e1 + e2 + e3);
      const float pr[4] = {e0 * inv, e1 * inv, e2 * inv, e3 * inv};
      float4 o0 = {0,0,0,0}, o1 = {0,0,0,0}, o2 = {0,0,0,0}, o3 = {0,0,0,0};
      #pragma unroll
      for (int lk = 0; lk < 4; ++lk) {
        const float* vb = &S.qkvf[(tl * 4 + lk) * 196 + 128 + hh * 16];
        const float4 v0 = *reinterpret_cast<const float4*>(vb);
        const float4 v1 = *reinterpret_cast<const float4*>(vb + 4);
        const float4 v2 = *reinterpret_cast<const float4*>(vb + 8);
        const float4 v3 = *reinterpret_cast<const float4*>(vb + 12);
        const float p = pr[lk];
        o0.x += p * v0.x; o0.y += p * v0.y; o0.z += p * v0.z; o0.w += p * v0.w;
        o1.x += p * v1.x; o1.y += p * v1.y; o1.z += p * v1.z; o1.w += p * v1.w;
        o2.x += p * v2.x; o2.y += p * v2.y; o2.z += p * v2.z; o2.w += p * v2.w;
        o3.x += p * v3.x; o3.y += p * v3.y; o3.z += p * v3.z; o3.w += p * v3.w;
      }
      // mean over queries folded into wOUT; raw o -> om[tl][lq*64 + hh*16 + d]
      unsigned short* om = S.emb;
      const int base = tl * 264 + lq * 64 + hh * 16;
      *reinterpret_cast<uint4*>(&om[base]) =
          make_uint4(pack2(o0.x, o0.y), pack2(o0.z, o0.w), pack2(o1.x, o1.y), pack2(o1.z, o1.w));
      *reinterpret_cast<uint4*>(&om[base + 8]) =
          make_uint4(pack2(o2.x, o2.y), pack2(o2.z, o2.w), pack2(o3.x, o3.y), pack2(o3.z, o3.w));
    }
    __syncthreads();

    // ---- out-proj (K=256, mean folded): ctx^T -> LDS feat rows s*16.. ----
    {
      f32x4 acc = Z;
      #pragma unroll
      for (int kk = 0; kk < 8; ++kk)
        acc = mfma16(wOUT[kk], LDBACT(S.emb, 264, 0, kk), acc);
      const int oc0 = wv * 16 + quad * 4;
      uint2 u;
      u.x = pack2(acc[0] + S.bout[oc0],     acc[1] + S.bout[oc0 + 1]);
      u.y = pack2(acc[2] + S.bout[oc0 + 2], acc[3] + S.bout[oc0 + 3]);
      *reinterpret_cast<uint2*>(&S.feat[(s * 16 + m) * 200 + oc0]) = u;
    }
    // no barrier: next layer1 writes S.h (attn readers of qkvf passed barrier);
    // feat readers are behind the post-loop barrier.
  }
  __syncthreads();

  // ================= B-part: 64 TLs =================
  // ---- phase L1 MFMA (K=32 zero-padded) -> ph ----
  {
    f32x4 acc[2][4];
    #pragma unroll
    for (int Mi = 0; Mi < 2; ++Mi)
      #pragma unroll
      for (int Nt = 0; Nt < 4; ++Nt) acc[Mi][Nt] = Z;
    #pragma unroll
    for (int Nt = 0; Nt < 4; ++Nt) {
      const bfrag b = LDBACT(S.xbuf, 32, Nt, 0);
      acc[0][Nt] = mfma16(wP1[0], b, acc[0][Nt]);
      acc[1][Nt] = mfma16(wP1[1], b, acc[1][Nt]);
    }
    #pragma unroll
    for (int Mi = 0; Mi < 2; ++Mi) {
      const int oc0 = (wv * 2 + Mi) * 16 + quad * 4;
      const f32x4 bb = *reinterpret_cast<const f32x4*>(&S.pb1[oc0]);
      #pragma unroll
      for (int Nt = 0; Nt < 4; ++Nt) {
        const int row = Nt * 16 + m;
        uint2 u;
        u.x = pack2(fmaxf(acc[Mi][Nt][0] + bb[0], 0.f), fmaxf(acc[Mi][Nt][1] + bb[1], 0.f));
        u.y = pack2(fmaxf(acc[Mi][Nt][2] + bb[2], 0.f), fmaxf(acc[Mi][Nt][3] + bb[3], 0.f));
        *reinterpret_cast<uint2*>(&S.ph[row * 136 + oc0]) = u;
      }
    }
  }
  __syncthreads();

  // ---- phase L2 (K=128) -> feat cols 64..191 ----
  {
    f32x4 acc[2][4];
    #pragma unroll
    for (int Mi = 0; Mi < 2; ++Mi)
      #pragma unroll
      for (int Nt = 0; Nt < 4; ++Nt) acc[Mi][Nt] = Z;
    #pragma unroll
    for (int kk = 0; kk < 4; ++kk)
      #pragma unroll
      for (int Nt = 0; Nt < 4; ++Nt) {
        const bfrag b = LDBACT(S.ph, 136, Nt, kk);
        acc[0][Nt] = mfma16(wP2[0][kk], b, acc[0][Nt]);
        acc[1][Nt] = mfma16(wP2[1][kk], b, acc[1][Nt]);
      }
    #pragma unroll
    for (int Mi = 0; Mi < 2; ++Mi) {
      const int oc0 = (wv * 2 + Mi) * 16 + quad * 4;
      const f32x4 bb = *reinterpret_cast<const f32x4*>(&S.pb2[oc0]);
      #pragma unroll
      for (int Nt = 0; Nt < 4; ++Nt) {
        const int row = Nt * 16 + m;
        uint2 u;
        u.x = pack2(fmaxf(acc[Mi][Nt][0] + bb[0], 0.f), fmaxf(acc[Mi][Nt][1] + bb[1], 0.f));
        u.y = pack2(fmaxf(acc[Mi][Nt][2] + bb[2], 0.f), fmaxf(acc[Mi][Nt][3] + bb[3], 0.f));
        *reinterpret_cast<uint2*>(&S.feat[row * 200 + 64 + oc0]) = u;
      }
    }
  }
  __syncthreads();

  // ---- head L1 (K=192) with per-region bias -> ph (overlay) ----
  {
    f32x4 acc[2][4];
    #pragma unroll
    for (int Mi = 0; Mi < 2; ++Mi)
      #pragma unroll
      for (int Nt = 0; Nt < 4; ++Nt) acc[Mi][Nt] = Z;
    #pragma unroll
    for (int kk = 0; kk < 6; ++kk)
      #pragma unroll
      for (int Nt = 0; Nt < 4; ++Nt) {
        const bfrag b = LDBACT(S.feat, 200, Nt, kk);
        acc[0][Nt] = mfma16(wH1[0][kk], b, acc[0][Nt]);
        acc[1][Nt] = mfma16(wH1[1][kk], b, acc[1][Nt]);
      }
    #pragma unroll
    for (int Mi = 0; Mi < 2; ++Mi) {
      const int oc0 = (wv * 2 + Mi) * 16 + quad * 4;
      #pragma unroll
      for (int Nt = 0; Nt < 4; ++Nt) {
        const int row = Nt * 16 + m;
        const f32x4 bb = *reinterpret_cast<const f32x4*>(&S.rbias[S.ridx[row]][oc0]);
        uint2 u;
        u.x = pack2(fmaxf(acc[Mi][Nt][0] + bb[0], 0.f), fmaxf(acc[Mi][Nt][1] + bb[1], 0.f));
        u.y = pack2(fmaxf(acc[Mi][Nt][2] + bb[2], 0.f), fmaxf(acc[Mi][Nt][3] + bb[3], 0.f));
        *reinterpret_cast<uint2*>(&S.ph[row * 136 + oc0]) = u;
      }
    }
  }
  __syncthreads();

  // ---- head L2 (128->1) + gaussian: 4 threads/TL ----
  {
    const int tl = tid >> 2, s4 = tid & 3;   // 64 TLs x 4 threads
    const unsigned short* hp = &S.ph[tl * 136 + s4 * 32];
    float t = 0.f;
    #pragma unroll
    for (int seg = 0; seg < 4; ++seg) {
      const bfrag hseg = *reinterpret_cast<const bfrag*>(hp + seg * 8);
      const float* w = &S.hw2[s4 * 32 + seg * 8];
      #pragma unroll
      for (int j = 0; j < 8; ++j)
        t += __uint_as_float(((unsigned int)(unsigned short)hseg[j]) << 16) * w[j];
    }
    t += __shfl_xor(t, 1);
    t += __shfl_xor(t, 2);
    if (s4 == 0) {
      const int n = n0 + tl;
      const float means = t + S.consts[0];
      const float ls = S.consts[1];
      const float nz = noise[n];
      const float a = means + __expf(ls) * nz;
      out[n] = fminf(fmaxf(a, -1.f), 1.f);
      // (actions - means) == std*noise exactly -> log_prob independent of means
      out[N_TL + n] = -0.5f * (nz * nz + 2.f * ls + 1.8378770664093453f);
    }
  }
}

extern "C" void kernel_launch(void* const* d_in, const int* in_sizes, int n_in,
                              void* d_out, int out_size, void* d_ws, size_t ws_size,
                              hipStream_t stream) {
  const float* queue        = (const float*)d_in[0];
  const float* waiting      = (const float*)d_in[1];
  const float* phase_onehot = (const float*)d_in[2];
  const float* elapsed      = (const float*)d_in[3];
  const int*   region_ids   = (const int*)d_in[4];
  const float* noise        = (const float*)d_in[5];
  const float* lane_w1      = (const float*)d_in[6];
  const float* lane_b1      = (const float*)d_in[7];
  const float* lane_w2      = (const float*)d_in[8];
  const float* lane_b2      = (const float*)d_in[9];
  const float* attn_in_w    = (const float*)d_in[10];
  const float* attn_in_b    = (const float*)d_in[11];
  const float* attn_out_w   = (const float*)d_in[12];
  const float* attn_out_b   = (const float*)d_in[13];
  const float* phase_w1     = (const float*)d_in[14];
  const float* phase_b1     = (const float*)d_in[15];
  const float* phase_w2     = (const float*)d_in[16];
  const float* phase_b2     = (const float*)d_in[17];
  const float* region_table = (const float*)d_in[18];
  const float* head_w1      = (const float*)d_in[19];
  const float* head_b1      = (const float*)d_in[20];
  const float* head_w2      = (const float*)d_in[21];
  const float* head_b2      = (const float*)d_in[22];
  const float* log_std      = (const float*)d_in[23];

  float* out = (float*)d_out;
  (void)d_ws; (void)ws_size;

  hipLaunchKernelGGL(fused_policy, dim3(GRID), dim3(BLK), 0, stream,
                     queue, waiting, phase_onehot, elapsed, region_ids, noise,
                     lane_w1, lane_b1, lane_w2, lane_b2,
                     attn_in_w, attn_in_b, attn_out_w, attn_out_b,
                     phase_w1, phase_b1, phase_w2, phase_b2, region_table,
                     head_w1, head_b1, head_w2, head_b2, log_std, out);
}

// Round 7
// 300.008 us; speedup vs baseline: 1.0382x; 1.0382x over previous
//
#include <hip/hip_runtime.h>
#include <math.h>

#define N_TL 131072
#define GRID 2048          // 64 TLs per block, single pass
#define BLK 256

typedef __attribute__((ext_vector_type(8))) short bfrag;
typedef __attribute__((ext_vector_type(4))) float f32x4;

// RNE bf16 (weights, staged once)
__device__ __forceinline__ unsigned short f2bf_rne(float x) {
  unsigned int u = __float_as_uint(x);
  return (unsigned short)((u + 0x7fffu + ((u >> 16) & 1u)) >> 16);
}
// cheap round-half-up pack of 2 floats -> bf16x2 (activations)
__device__ __forceinline__ unsigned int pack2(float a, float b) {
  return ((__float_as_uint(a) + 0x8000u) >> 16) |
         ((__float_as_uint(b) + 0x8000u) & 0xffff0000u);
}
__device__ __forceinline__ float bf2f(unsigned short u) {
  return __uint_as_float(((unsigned int)u) << 16);
}
__device__ __forceinline__ f32x4 mfma16(bfrag a, bfrag b, f32x4 c) {
  return __builtin_amdgcn_mfma_f32_16x16x32_bf16(a, b, c, 0, 0, 0);
}

// Weight A-fragment (W^T): A[m=col0+(lane&15)][k=k0+quad*8+j] = W[k][col]*scale, 0 for k>=K.
__device__ __forceinline__ bfrag load_wfragT(const float* __restrict__ w, int ncols,
                                             int col0, int k0, int lane, int K, float scale) {
  const int mm = lane & 15, qq = lane >> 4;
  bfrag f;
  #pragma unroll
  for (int j = 0; j < 8; ++j) {
    const int k = k0 + qq * 8 + j;
    const float v = (k < K) ? w[(size_t)k * ncols + col0 + mm] * scale : 0.f;
    f[j] = (short)f2bf_rne(v);
  }
  return f;
}

// B-operand (activations) from row-major bf16 LDS
#define LDBACT(arr, stride, nt, kk) \
  (*reinterpret_cast<const bfrag*>(&(arr)[((nt) * 16 + m) * (stride) + (kk) * 32 + quad * 8]))

// LDS: ~70 KB -> 2 blocks/CU
struct alignas(16) SmemF {
  union {
    unsigned short qkv[64 * 200];  // qkv bf16 during A attention (25.6 KB)
    unsigned short h[64 * 136];    // layer1 out bf16 (dead before qkv write)
    unsigned short ph[64 * 136];   // B: pL1 out; head-L1 out (A-part dead)
  };
  unsigned short emb[64 * 72];     // emb; om[16][264] overlays (9.2 KB)
  unsigned short xbuf[64 * 32];    // A layer1 input / B phase-L1 input (4 KB)
  unsigned short feat[64 * 200];   // [ctx(64) | phase_emb(128)] persists A->B (25.6 KB)
  float b1[128], b2[64], bin[192], bout[64];
  float pb1[128], pb2[128];
  float rbias[4][128];             // head_b1 + region[g] @ head_w1[192:200,:]
  float hw2[128];
  float consts[2];
  int ridx[64];
};

__global__ __launch_bounds__(BLK, 2)
void fused_policy(const float* __restrict__ queue,
                  const float* __restrict__ waiting,
                  const float* __restrict__ phase_onehot,
                  const float* __restrict__ elapsed,
                  const int* __restrict__ region_ids,
                  const float* __restrict__ noise,
                  const float* __restrict__ lane_w1,
                  const float* __restrict__ lane_b1,
                  const float* __restrict__ lane_w2,
                  const float* __restrict__ lane_b2,
                  const float* __restrict__ attn_in_w,
                  const float* __restrict__ attn_in_b,
                  const float* __restrict__ attn_out_w,
                  const float* __restrict__ attn_out_b,
                  const float* __restrict__ phase_w1,
                  const float* __restrict__ phase_b1,
                  const float* __restrict__ phase_w2,
                  const float* __restrict__ phase_b2,
                  const float* __restrict__ region_table,
                  const float* __restrict__ head_w1,
                  const float* __restrict__ head_b1,
                  const float* __restrict__ head_w2,
                  const float* __restrict__ head_b2,
                  const float* __restrict__ log_std,
                  float* __restrict__ out) {
  __shared__ SmemF S;
  const int tid  = threadIdx.x;
  const int wv   = tid >> 6;
  const int lane = tid & 63;
  const int m    = lane & 15;
  const int quad = lane >> 4;
  const int n0   = blockIdx.x * 64;         // 64 TLs per block
  const f32x4 Z = {0.f, 0.f, 0.f, 0.f};

  // ---- A-part register weight fragments (20 frags) ----
  bfrag wL1[2], wL2[4], wQKV[3][2], wOUT[8];
  #pragma unroll
  for (int Mi = 0; Mi < 2; ++Mi)
    wL1[Mi] = load_wfragT(lane_w1, 128, (wv * 2 + Mi) * 16, 0, lane, 3, 1.f);
  #pragma unroll
  for (int kk = 0; kk < 4; ++kk)
    wL2[kk] = load_wfragT(lane_w2, 64, wv * 16, kk * 32, lane, 128, 1.f);
  #pragma unroll
  for (int Mi = 0; Mi < 3; ++Mi)
    #pragma unroll
    for (int kk = 0; kk < 2; ++kk)
      wQKV[Mi][kk] = load_wfragT(attn_in_w, 192, (wv + Mi * 4) * 16, kk * 32, lane, 64,
                                 Mi == 0 ? 0.25f : 1.f);   // fold 1/sqrt(HD) into Q
  #pragma unroll
  for (int kk = 0; kk < 8; ++kk) {          // out-proj, query-mean folded (K=256)
    bfrag f;
    #pragma unroll
    for (int j = 0; j < 8; ++j) {
      const int k = kk * 32 + quad * 8 + j;
      f[j] = (short)f2bf_rne(attn_out_w[(size_t)(k & 63) * 64 + wv * 16 + m] * 0.25f);
    }
    wOUT[kk] = f;
  }
  // ---- B-part register weight fragments (22 frags): wave owns col tiles {2wv, 2wv+1} ----
  bfrag wP1[2], wP2[2][4], wH1[2][6];
  #pragma unroll
  for (int Mi = 0; Mi < 2; ++Mi) {
    wP1[Mi] = load_wfragT(phase_w1, 128, (wv * 2 + Mi) * 16, 0, lane, 5, 1.f);
    #pragma unroll
    for (int kk = 0; kk < 4; ++kk)
      wP2[Mi][kk] = load_wfragT(phase_w2, 128, (wv * 2 + Mi) * 16, kk * 32, lane, 128, 1.f);
    #pragma unroll
    for (int kk = 0; kk < 6; ++kk)
      wH1[Mi][kk] = load_wfragT(head_w1, 128, (wv * 2 + Mi) * 16, kk * 32, lane, 192, 1.f);
  }

  // ---- stage biases / constants ----
  for (int i = tid; i < 128; i += BLK) S.b1[i] = lane_b1[i];
  for (int i = tid; i < 64;  i += BLK) S.b2[i] = lane_b2[i];
  for (int i = tid; i < 192; i += BLK) S.bin[i] = attn_in_b[i] * ((i < 64) ? 0.25f : 1.f);
  for (int i = tid; i < 64;  i += BLK) S.bout[i] = attn_out_b[i];
  for (int i = tid; i < 128; i += BLK) S.pb1[i] = phase_b1[i];
  for (int i = tid; i < 128; i += BLK) S.pb2[i] = phase_b2[i];
  for (int i = tid; i < 128; i += BLK) S.hw2[i] = head_w2[i];
  for (int i = tid; i < 512; i += BLK) {
    const int g = i >> 7, c = i & 127;
    float acc = head_b1[c];
    #pragma unroll
    for (int j = 0; j < 8; ++j) acc += region_table[g * 8 + j] * head_w1[(192 + j) * 128 + c];
    S.rbias[g][c] = acc;
  }
  if (tid == 0) { S.consts[0] = head_b2[0]; S.consts[1] = log_std[0]; }
  if (tid < 64) {
    int r = region_ids[n0 + tid];
    S.ridx[tid] = r < 0 ? 0 : (r > 3 ? 3 : r);
  }
  // stage x for sub-iter 0 (16 TLs x 4 lane-rows, K padded to 32)
  {
    const int r = tid >> 2, seg = tid & 3;
    uint4 z = {0, 0, 0, 0};
    if (seg == 0) {
      const int gl = n0 * 4 + r;
      z.x = pack2(queue[gl], waiting[gl]);
      z.y = pack2(elapsed[n0 + (r >> 2)], 0.f);
    }
    *reinterpret_cast<uint4*>(&S.xbuf[r * 32 + seg * 8]) = z;
  }
  __syncthreads();

  // ================= A-part: 4 sub-iters of 16 TLs =================
  #pragma unroll 1
  for (int s = 0; s < 4; ++s) {
    const int tl0 = n0 + s * 16;

    // ---- layer1 MFMA (K=32 zero-padded): h^T = w1^T @ x ----
    {
      f32x4 acc[2][4];
      #pragma unroll
      for (int Mi = 0; Mi < 2; ++Mi)
        #pragma unroll
        for (int Nt = 0; Nt < 4; ++Nt) acc[Mi][Nt] = Z;
      #pragma unroll
      for (int Nt = 0; Nt < 4; ++Nt) {
        const bfrag b = LDBACT(S.xbuf, 32, Nt, 0);
        acc[0][Nt] = mfma16(wL1[0], b, acc[0][Nt]);
        acc[1][Nt] = mfma16(wL1[1], b, acc[1][Nt]);
      }
      #pragma unroll
      for (int Mi = 0; Mi < 2; ++Mi) {
        const int oc0 = (wv * 2 + Mi) * 16 + quad * 4;
        const f32x4 bb = *reinterpret_cast<const f32x4*>(&S.b1[oc0]);
        #pragma unroll
        for (int Nt = 0; Nt < 4; ++Nt) {
          const int row = Nt * 16 + m;
          uint2 u;
          u.x = pack2(fmaxf(acc[Mi][Nt][0] + bb[0], 0.f), fmaxf(acc[Mi][Nt][1] + bb[1], 0.f));
          u.y = pack2(fmaxf(acc[Mi][Nt][2] + bb[2], 0.f), fmaxf(acc[Mi][Nt][3] + bb[3], 0.f));
          *reinterpret_cast<uint2*>(&S.h[row * 136 + oc0]) = u;
        }
      }
    }
    __syncthreads();

    // ---- layer2: emb^T = w2^T @ h ----
    {
      f32x4 acc[4] = {Z, Z, Z, Z};
      #pragma unroll
      for (int Nt = 0; Nt < 4; ++Nt)
        #pragma unroll
        for (int kk = 0; kk < 4; ++kk)
          acc[Nt] = mfma16(wL2[kk], LDBACT(S.h, 136, Nt, kk), acc[Nt]);
      const int oc0 = wv * 16 + quad * 4;
      const f32x4 bb = *reinterpret_cast<const f32x4*>(&S.b2[oc0]);
      #pragma unroll
      for (int Nt = 0; Nt < 4; ++Nt) {
        const int row = Nt * 16 + m;
        uint2 u;
        u.x = pack2(fmaxf(acc[Nt][0] + bb[0], 0.f), fmaxf(acc[Nt][1] + bb[1], 0.f));
        u.y = pack2(fmaxf(acc[Nt][2] + bb[2], 0.f), fmaxf(acc[Nt][3] + bb[3], 0.f));
        *reinterpret_cast<uint2*>(&S.emb[row * 72 + oc0]) = u;
      }
    }
    __syncthreads();

    // ---- QKV: qkv^T = Win^T @ emb (bf16 out); stage next x / B input ----
    {
      f32x4 acc[3][4];
      #pragma unroll
      for (int Mi = 0; Mi < 3; ++Mi)
        #pragma unroll
        for (int Nt = 0; Nt < 4; ++Nt) acc[Mi][Nt] = Z;
      #pragma unroll
      for (int Nt = 0; Nt < 4; ++Nt) {
        const bfrag e0 = LDBACT(S.emb, 72, Nt, 0);
        const bfrag e1 = LDBACT(S.emb, 72, Nt, 1);
        #pragma unroll
        for (int Mi = 0; Mi < 3; ++Mi) {
          acc[Mi][Nt] = mfma16(wQKV[Mi][0], e0, acc[Mi][Nt]);
          acc[Mi][Nt] = mfma16(wQKV[Mi][1], e1, acc[Mi][Nt]);
        }
      }
      #pragma unroll
      for (int Mi = 0; Mi < 3; ++Mi) {
        const int oc0 = (wv + Mi * 4) * 16 + quad * 4;
        const f32x4 bb = *reinterpret_cast<const f32x4*>(&S.bin[oc0]);
        #pragma unroll
        for (int Nt = 0; Nt < 4; ++Nt) {
          const int row = Nt * 16 + m;
          uint2 u;
          u.x = pack2(acc[Mi][Nt][0] + bb[0], acc[Mi][Nt][1] + bb[1]);
          u.y = pack2(acc[Mi][Nt][2] + bb[2], acc[Mi][Nt][3] + bb[3]);
          *reinterpret_cast<uint2*>(&S.qkv[row * 200 + oc0]) = u;
        }
      }
      const int r = tid >> 2, seg = tid & 3;
      uint4 z = {0, 0, 0, 0};
      if (s < 3) {      // prefetch next sub-iter's lane inputs
        if (seg == 0) {
          const int gl = (tl0 + 16) * 4 + r;
          z.x = pack2(queue[gl], waiting[gl]);
          z.y = pack2(elapsed[tl0 + 16 + (r >> 2)], 0.f);
        }
      } else {          // stage B phase-L1 input (64 TLs, K padded to 32)
        if (seg == 0) {
          const float4 p = *reinterpret_cast<const float4*>(&phase_onehot[(n0 + r) * 4]);
          z.x = pack2(p.x, p.y);
          z.y = pack2(p.z, p.w);
          z.z = pack2(elapsed[n0 + r], 0.f);
        }
      }
      *reinterpret_cast<uint4*>(&S.xbuf[r * 32 + seg * 8]) = z;
    }
    __syncthreads();

    // ---- attention (bf16 loads, f32 math): 16 threads/TL = 4 heads x 4 queries ----
    {
      const int tl = tid >> 4, l16 = tid & 15;
      const int hh = l16 >> 2, lq = l16 & 3;
      float qf[16];
      {
        const unsigned short* qp = &S.qkv[(tl * 4 + lq) * 200 + hh * 16];
        const bfrag q0 = *reinterpret_cast<const bfrag*>(qp);
        const bfrag q1 = *reinterpret_cast<const bfrag*>(qp + 8);
        #pragma unroll
        for (int j = 0; j < 8; ++j) {
          qf[j]     = bf2f((unsigned short)q0[j]);
          qf[8 + j] = bf2f((unsigned short)q1[j]);
        }
      }
      float sc[4];
      #pragma unroll
      for (int lk = 0; lk < 4; ++lk) {
        const unsigned short* kp = &S.qkv[(tl * 4 + lk) * 200 + 64 + hh * 16];
        const bfrag k0 = *reinterpret_cast<const bfrag*>(kp);
        const bfrag k1 = *reinterpret_cast<const bfrag*>(kp + 8);
        float t = 0.f;
        #pragma unroll
        for (int j = 0; j < 8; ++j) {
          t += qf[j]     * bf2f((unsigned short)k0[j]);
          t += qf[8 + j] * bf2f((unsigned short)k1[j]);
        }
        sc[lk] = t;   // 1/sqrt(HD) folded into Q weights/bias
      }
      const float mx = fmaxf(fmaxf(sc[0], sc[1]), fmaxf(sc[2], sc[3]));
      const float e0 = __expf(sc[0] - mx), e1 = __expf(sc[1] - mx);
      const float e2 = __expf(sc[2] - mx), e3 = __expf(sc[3] - mx);
      const float inv = 1.f / (e0 + e1 + e2 + e3);
      const float pr[4] = {e0 * inv, e1 * inv, e2 * inv, e3 * inv};
      float o[16];
      #pragma unroll
      for (int j = 0; j < 16; ++j) o[j] = 0.f;
      #pragma unroll
      for (int lk = 0; lk < 4; ++lk) {
        const unsigned short* vp = &S.qkv[(tl * 4 + lk) * 200 + 128 + hh * 16];
        const bfrag v0 = *reinterpret_cast<const bfrag*>(vp);
        const bfrag v1 = *reinterpret_cast<const bfrag*>(vp + 8);
        const float p = pr[lk];
        #pragma unroll
        for (int j = 0; j < 8; ++j) {
          o[j]     += p * bf2f((unsigned short)v0[j]);
          o[8 + j] += p * bf2f((unsigned short)v1[j]);
        }
      }
      // mean over queries folded into wOUT; raw o -> om[tl][lq*64 + hh*16 + d]
      unsigned short* om = S.emb;
      const int base = tl * 264 + lq * 64 + hh * 16;
      *reinterpret_cast<uint4*>(&om[base]) =
          make_uint4(pack2(o[0], o[1]), pack2(o[2], o[3]), pack2(o[4], o[5]), pack2(o[6], o[7]));
      *reinterpret_cast<uint4*>(&om[base + 8]) =
          make_uint4(pack2(o[8], o[9]), pack2(o[10], o[11]), pack2(o[12], o[13]), pack2(o[14], o[15]));
    }
    __syncthreads();

    // ---- out-proj (K=256, mean folded): ctx^T -> LDS feat rows s*16.. ----
    {
      f32x4 acc = Z;
      #pragma unroll
      for (int kk = 0; kk < 8; ++kk)
        acc = mfma16(wOUT[kk], LDBACT(S.emb, 264, 0, kk), acc);
      const int oc0 = wv * 16 + quad * 4;
      uint2 u;
      u.x = pack2(acc[0] + S.bout[oc0],     acc[1] + S.bout[oc0 + 1]);
      u.y = pack2(acc[2] + S.bout[oc0 + 2], acc[3] + S.bout[oc0 + 3]);
      *reinterpret_cast<uint2*>(&S.feat[(s * 16 + m) * 200 + oc0]) = u;
    }
    // no barrier: next layer1 writes S.h (attn readers of qkv passed barrier);
    // feat readers are behind the post-loop barrier.
  }
  __syncthreads();

  // ================= B-part: 64 TLs =================
  // ---- phase L1 MFMA (K=32 zero-padded) -> ph ----
  {
    f32x4 acc[2][4];
    #pragma unroll
    for (int Mi = 0; Mi < 2; ++Mi)
      #pragma unroll
      for (int Nt = 0; Nt < 4; ++Nt) acc[Mi][Nt] = Z;
    #pragma unroll
    for (int Nt = 0; Nt < 4; ++Nt) {
      const bfrag b = LDBACT(S.xbuf, 32, Nt, 0);
      acc[0][Nt] = mfma16(wP1[0], b, acc[0][Nt]);
      acc[1][Nt] = mfma16(wP1[1], b, acc[1][Nt]);
    }
    #pragma unroll
    for (int Mi = 0; Mi < 2; ++Mi) {
      const int oc0 = (wv * 2 + Mi) * 16 + quad * 4;
      const f32x4 bb = *reinterpret_cast<const f32x4*>(&S.pb1[oc0]);
      #pragma unroll
      for (int Nt = 0; Nt < 4; ++Nt) {
        const int row = Nt * 16 + m;
        uint2 u;
        u.x = pack2(fmaxf(acc[Mi][Nt][0] + bb[0], 0.f), fmaxf(acc[Mi][Nt][1] + bb[1], 0.f));
        u.y = pack2(fmaxf(acc[Mi][Nt][2] + bb[2], 0.f), fmaxf(acc[Mi][Nt][3] + bb[3], 0.f));
        *reinterpret_cast<uint2*>(&S.ph[row * 136 + oc0]) = u;
      }
    }
  }
  __syncthreads();

  // ---- phase L2 (K=128) -> feat cols 64..191 ----
  {
    f32x4 acc[2][4];
    #pragma unroll
    for (int Mi = 0; Mi < 2; ++Mi)
      #pragma unroll
      for (int Nt = 0; Nt < 4; ++Nt) acc[Mi][Nt] = Z;
    #pragma unroll
    for (int kk = 0; kk < 4; ++kk)
      #pragma unroll
      for (int Nt = 0; Nt < 4; ++Nt) {
        const bfrag b = LDBACT(S.ph, 136, Nt, kk);
        acc[0][Nt] = mfma16(wP2[0][kk], b, acc[0][Nt]);
        acc[1][Nt] = mfma16(wP2[1][kk], b, acc[1][Nt]);
      }
    #pragma unroll
    for (int Mi = 0; Mi < 2; ++Mi) {
      const int oc0 = (wv * 2 + Mi) * 16 + quad * 4;
      const f32x4 bb = *reinterpret_cast<const f32x4*>(&S.pb2[oc0]);
      #pragma unroll
      for (int Nt = 0; Nt < 4; ++Nt) {
        const int row = Nt * 16 + m;
        uint2 u;
        u.x = pack2(fmaxf(acc[Mi][Nt][0] + bb[0], 0.f), fmaxf(acc[Mi][Nt][1] + bb[1], 0.f));
        u.y = pack2(fmaxf(acc[Mi][Nt][2] + bb[2], 0.f), fmaxf(acc[Mi][Nt][3] + bb[3], 0.f));
        *reinterpret_cast<uint2*>(&S.feat[row * 200 + 64 + oc0]) = u;
      }
    }
  }
  __syncthreads();

  // ---- head L1 (K=192) with per-region bias -> ph (overlay) ----
  {
    f32x4 acc[2][4];
    #pragma unroll
    for (int Mi = 0; Mi < 2; ++Mi)
      #pragma unroll
      for (int Nt = 0; Nt < 4; ++Nt) acc[Mi][Nt] = Z;
    #pragma unroll
    for (int kk = 0; kk < 6; ++kk)
      #pragma unroll
      for (int Nt = 0; Nt < 4; ++Nt) {
        const bfrag b = LDBACT(S.feat, 200, Nt, kk);
        acc[0][Nt] = mfma16(wH1[0][kk], b, acc[0][Nt]);
        acc[1][Nt] = mfma16(wH1[1][kk], b, acc[1][Nt]);
      }
    #pragma unroll
    for (int Mi = 0; Mi < 2; ++Mi) {
      const int oc0 = (wv * 2 + Mi) * 16 + quad * 4;
      #pragma unroll
      for (int Nt = 0; Nt < 4; ++Nt) {
        const int row = Nt * 16 + m;
        const f32x4 bb = *reinterpret_cast<const f32x4*>(&S.rbias[S.ridx[row]][oc0]);
        uint2 u;
        u.x = pack2(fmaxf(acc[Mi][Nt][0] + bb[0], 0.f), fmaxf(acc[Mi][Nt][1] + bb[1], 0.f));
        u.y = pack2(fmaxf(acc[Mi][Nt][2] + bb[2], 0.f), fmaxf(acc[Mi][Nt][3] + bb[3], 0.f));
        *reinterpret_cast<uint2*>(&S.ph[row * 136 + oc0]) = u;
      }
    }
  }
  __syncthreads();

  // ---- head L2 (128->1) + gaussian: 4 threads/TL ----
  {
    const int tl = tid >> 2, s4 = tid & 3;   // 64 TLs x 4 threads
    const unsigned short* hp = &S.ph[tl * 136 + s4 * 32];
    float t = 0.f;
    #pragma unroll
    for (int seg = 0; seg < 4; ++seg) {
      const bfrag hseg = *reinterpret_cast<const bfrag*>(hp + seg * 8);
      const float* w = &S.hw2[s4 * 32 + seg * 8];
      #pragma unroll
      for (int j = 0; j < 8; ++j)
        t += bf2f((unsigned short)hseg[j]) * w[j];
    }
    t += __shfl_xor(t, 1);
    t += __shfl_xor(t, 2);
    if (s4 == 0) {
      const int n = n0 + tl;
      const float means = t + S.consts[0];
      const float ls = S.consts[1];
      const float nz = noise[n];
      const float a = means + __expf(ls) * nz;
      out[n] = fminf(fmaxf(a, -1.f), 1.f);
      // (actions - means) == std*noise exactly -> log_prob independent of means
      out[N_TL + n] = -0.5f * (nz * nz + 2.f * ls + 1.8378770664093453f);
    }
  }
}

extern "C" void kernel_launch(void* const* d_in, const int* in_sizes, int n_in,
                              void* d_out, int out_size, void* d_ws, size_t ws_size,
                              hipStream_t stream) {
  const float* queue        = (const float*)d_in[0];
  const float* waiting      = (const float*)d_in[1];
  const float* phase_onehot = (const float*)d_in[2];
  const float* elapsed      = (const float*)d_in[3];
  const int*   region_ids   = (const int*)d_in[4];
  const float* noise        = (const float*)d_in[5];
  const float* lane_w1      = (const float*)d_in[6];
  const float* lane_b1      = (const float*)d_in[7];
  const float* lane_w2      = (const float*)d_in[8];
  const float* lane_b2      = (const float*)d_in[9];
  const float* attn_in_w    = (const float*)d_in[10];
  const float* attn_in_b    = (const float*)d_in[11];
  const float* attn_out_w   = (const float*)d_in[12];
  const float* attn_out_b   = (const float*)d_in[13];
  const float* phase_w1     = (const float*)d_in[14];
  const float* phase_b1     = (const float*)d_in[15];
  const float* phase_w2     = (const float*)d_in[16];
  const float* phase_b2     = (const float*)d_in[17];
  const float* region_table = (const float*)d_in[18];
  const float* head_w1      = (const float*)d_in[19];
  const float* head_b1      = (const float*)d_in[20];
  const float* head_w2      = (const float*)d_in[21];
  const float* head_b2      = (const float*)d_in[22];
  const float* log_std      = (const float*)d_in[23];

  float* out = (float*)d_out;
  (void)d_ws; (void)ws_size;

  hipLaunchKernelGGL(fused_policy, dim3(GRID), dim3(BLK), 0, stream,
                     queue, waiting, phase_onehot, elapsed, region_ids, noise,
                     lane_w1, lane_b1, lane_w2, lane_b2,
                     attn_in_w, attn_in_b, attn_out_w, attn_out_b,
                     phase_w1, phase_b1, phase_w2, phase_b2, region_table,
                     head_w1, head_b1, head_w2, head_b2, log_std, out);
}

// Round 8
// 208.316 us; speedup vs baseline: 1.4952x; 1.4402x over previous
//
#include <hip/hip_runtime.h>
#include <math.h>

#define N_TL 131072
#define GRID 2048          // 64 TLs per block, single pass
#define BLK 256

typedef __attribute__((ext_vector_type(8))) short bfrag;
typedef __attribute__((ext_vector_type(4))) float f32x4;

// RNE bf16 (weights, staged once)
__device__ __forceinline__ unsigned short f2bf_rne(float x) {
  unsigned int u = __float_as_uint(x);
  return (unsigned short)((u + 0x7fffu + ((u >> 16) & 1u)) >> 16);
}
// cheap round-half-up pack of 2 floats -> bf16x2 (activations)
__device__ __forceinline__ unsigned int pack2(float a, float b) {
  return ((__float_as_uint(a) + 0x8000u) >> 16) |
         ((__float_as_uint(b) + 0x8000u) & 0xffff0000u);
}
__device__ __forceinline__ float bf2f(unsigned short u) {
  return __uint_as_float(((unsigned int)u) << 16);
}
__device__ __forceinline__ f32x4 mfma16(bfrag a, bfrag b, f32x4 c) {
  return __builtin_amdgcn_mfma_f32_16x16x32_bf16(a, b, c, 0, 0, 0);
}

// Weight A-fragment (W^T): A[m=col0+(lane&15)][k=k0+quad*8+j] = W[k][col]*scale, 0 for k>=K.
__device__ __forceinline__ bfrag load_wfragT(const float* __restrict__ w, int ncols,
                                             int col0, int k0, int lane, int K, float scale) {
  const int mm = lane & 15, qq = lane >> 4;
  bfrag f;
  #pragma unroll
  for (int j = 0; j < 8; ++j) {
    const int k = k0 + qq * 8 + j;
    const float v = (k < K) ? w[(size_t)k * ncols + col0 + mm] * scale : 0.f;
    f[j] = (short)f2bf_rne(v);
  }
  return f;
}

// B-operand (activations) from row-major bf16 LDS
#define LDBACT(arr, stride, nt, kk) \
  (*reinterpret_cast<const bfrag*>(&(arr)[((nt) * 16 + m) * (stride) + (kk) * 32 + quad * 8]))

// LDS: ~70 KB -> 2 blocks/CU
struct alignas(16) SmemF {
  union {
    unsigned short qkv[64 * 200];  // qkv bf16 during A attention (25.6 KB)
    unsigned short h[64 * 136];    // layer1 out bf16 (dead before qkv write)
    unsigned short ph[64 * 136];   // B: pL1 out; head-L1 out (A-part dead)
  };
  unsigned short emb[64 * 72];     // emb; om[16][264] overlays (9.2 KB)
  unsigned short xbuf[64 * 32];    // A layer1 input / B phase-L1 input (4 KB)
  unsigned short feat[64 * 200];   // [ctx(64) | phase_emb(128)] persists A->B (25.6 KB)
  float b1[128], b2[64], bin[192], bout[64];
  float pb1[128], pb2[128];
  float rbias[4][128];             // head_b1 + region[g] @ head_w1[192:200,:]
  float hw2[128];
  float consts[2];
  int ridx[64];
};

__global__ __launch_bounds__(BLK, 2)
void fused_policy(const float* __restrict__ queue,
                  const float* __restrict__ waiting,
                  const float* __restrict__ phase_onehot,
                  const float* __restrict__ elapsed,
                  const int* __restrict__ region_ids,
                  const float* __restrict__ noise,
                  const float* __restrict__ lane_w1,
                  const float* __restrict__ lane_b1,
                  const float* __restrict__ lane_w2,
                  const float* __restrict__ lane_b2,
                  const float* __restrict__ attn_in_w,
                  const float* __restrict__ attn_in_b,
                  const float* __restrict__ attn_out_w,
                  const float* __restrict__ attn_out_b,
                  const float* __restrict__ phase_w1,
                  const float* __restrict__ phase_b1,
                  const float* __restrict__ phase_w2,
                  const float* __restrict__ phase_b2,
                  const float* __restrict__ region_table,
                  const float* __restrict__ head_w1,
                  const float* __restrict__ head_b1,
                  const float* __restrict__ head_w2,
                  const float* __restrict__ head_b2,
                  const float* __restrict__ log_std,
                  float* __restrict__ out) {
  __shared__ SmemF S;
  const int tid  = threadIdx.x;
  const int wv   = tid >> 6;
  const int lane = tid & 63;
  const int m    = lane & 15;
  const int quad = lane >> 4;
  const int n0   = blockIdx.x * 64;         // 64 TLs per block
  const f32x4 Z = {0.f, 0.f, 0.f, 0.f};

  // ---- A-part register weight fragments (14 frags; B frags loaded AFTER A loop) ----
  bfrag wL1[2], wL2[4], wQKV[3][2], wOUT2[2];
  #pragma unroll
  for (int Mi = 0; Mi < 2; ++Mi)
    wL1[Mi] = load_wfragT(lane_w1, 128, (wv * 2 + Mi) * 16, 0, lane, 3, 1.f);
  #pragma unroll
  for (int kk = 0; kk < 4; ++kk)
    wL2[kk] = load_wfragT(lane_w2, 64, wv * 16, kk * 32, lane, 128, 1.f);
  #pragma unroll
  for (int Mi = 0; Mi < 3; ++Mi)
    #pragma unroll
    for (int kk = 0; kk < 2; ++kk)
      wQKV[Mi][kk] = load_wfragT(attn_in_w, 192, (wv + Mi * 4) * 16, kk * 32, lane, 64,
                                 Mi == 0 ? 0.25f : 1.f);   // fold 1/sqrt(HD) into Q
  // out-proj with query-mean folded: K=256, W'[k][c] = Wout[k&63][c]*0.25.
  // k&63 depends only on kk&1 -> 2 distinct frags, each used 4x.
  #pragma unroll
  for (int kk = 0; kk < 2; ++kk) {
    bfrag f;
    #pragma unroll
    for (int j = 0; j < 8; ++j) {
      const int k = kk * 32 + quad * 8 + j;
      f[j] = (short)f2bf_rne(attn_out_w[(size_t)k * 64 + wv * 16 + m] * 0.25f);
    }
    wOUT2[kk] = f;
  }

  // ---- stage biases / constants ----
  for (int i = tid; i < 128; i += BLK) S.b1[i] = lane_b1[i];
  for (int i = tid; i < 64;  i += BLK) S.b2[i] = lane_b2[i];
  for (int i = tid; i < 192; i += BLK) S.bin[i] = attn_in_b[i] * ((i < 64) ? 0.25f : 1.f);
  for (int i = tid; i < 64;  i += BLK) S.bout[i] = attn_out_b[i];
  for (int i = tid; i < 128; i += BLK) S.pb1[i] = phase_b1[i];
  for (int i = tid; i < 128; i += BLK) S.pb2[i] = phase_b2[i];
  for (int i = tid; i < 128; i += BLK) S.hw2[i] = head_w2[i];
  for (int i = tid; i < 512; i += BLK) {
    const int g = i >> 7, c = i & 127;
    float acc = head_b1[c];
    #pragma unroll
    for (int j = 0; j < 8; ++j) acc += region_table[g * 8 + j] * head_w1[(192 + j) * 128 + c];
    S.rbias[g][c] = acc;
  }
  if (tid == 0) { S.consts[0] = head_b2[0]; S.consts[1] = log_std[0]; }
  if (tid < 64) {
    int r = region_ids[n0 + tid];
    S.ridx[tid] = r < 0 ? 0 : (r > 3 ? 3 : r);
  }
  // stage x for sub-iter 0 (16 TLs x 4 lane-rows, K padded to 32)
  {
    const int r = tid >> 2, seg = tid & 3;
    uint4 z = {0, 0, 0, 0};
    if (seg == 0) {
      const int gl = n0 * 4 + r;
      z.x = pack2(queue[gl], waiting[gl]);
      z.y = pack2(elapsed[n0 + (r >> 2)], 0.f);
    }
    *reinterpret_cast<uint4*>(&S.xbuf[r * 32 + seg * 8]) = z;
  }
  __syncthreads();

  // ================= A-part: 4 sub-iters of 16 TLs =================
  #pragma unroll 1
  for (int s = 0; s < 4; ++s) {
    const int tl0 = n0 + s * 16;

    // ---- layer1 MFMA (K=32 zero-padded): h^T = w1^T @ x ----
    {
      f32x4 acc[2][4];
      #pragma unroll
      for (int Mi = 0; Mi < 2; ++Mi)
        #pragma unroll
        for (int Nt = 0; Nt < 4; ++Nt) acc[Mi][Nt] = Z;
      #pragma unroll
      for (int Nt = 0; Nt < 4; ++Nt) {
        const bfrag b = LDBACT(S.xbuf, 32, Nt, 0);
        acc[0][Nt] = mfma16(wL1[0], b, acc[0][Nt]);
        acc[1][Nt] = mfma16(wL1[1], b, acc[1][Nt]);
      }
      #pragma unroll
      for (int Mi = 0; Mi < 2; ++Mi) {
        const int oc0 = (wv * 2 + Mi) * 16 + quad * 4;
        const f32x4 bb = *reinterpret_cast<const f32x4*>(&S.b1[oc0]);
        #pragma unroll
        for (int Nt = 0; Nt < 4; ++Nt) {
          const int row = Nt * 16 + m;
          uint2 u;
          u.x = pack2(fmaxf(acc[Mi][Nt][0] + bb[0], 0.f), fmaxf(acc[Mi][Nt][1] + bb[1], 0.f));
          u.y = pack2(fmaxf(acc[Mi][Nt][2] + bb[2], 0.f), fmaxf(acc[Mi][Nt][3] + bb[3], 0.f));
          *reinterpret_cast<uint2*>(&S.h[row * 136 + oc0]) = u;
        }
      }
    }
    __syncthreads();

    // ---- layer2: emb^T = w2^T @ h ----
    {
      f32x4 acc[4] = {Z, Z, Z, Z};
      #pragma unroll
      for (int Nt = 0; Nt < 4; ++Nt)
        #pragma unroll
        for (int kk = 0; kk < 4; ++kk)
          acc[Nt] = mfma16(wL2[kk], LDBACT(S.h, 136, Nt, kk), acc[Nt]);
      const int oc0 = wv * 16 + quad * 4;
      const f32x4 bb = *reinterpret_cast<const f32x4*>(&S.b2[oc0]);
      #pragma unroll
      for (int Nt = 0; Nt < 4; ++Nt) {
        const int row = Nt * 16 + m;
        uint2 u;
        u.x = pack2(fmaxf(acc[Nt][0] + bb[0], 0.f), fmaxf(acc[Nt][1] + bb[1], 0.f));
        u.y = pack2(fmaxf(acc[Nt][2] + bb[2], 0.f), fmaxf(acc[Nt][3] + bb[3], 0.f));
        *reinterpret_cast<uint2*>(&S.emb[row * 72 + oc0]) = u;
      }
    }
    __syncthreads();

    // ---- QKV: qkv^T = Win^T @ emb (bf16 out); stage next x / B input ----
    {
      f32x4 acc[3][4];
      #pragma unroll
      for (int Mi = 0; Mi < 3; ++Mi)
        #pragma unroll
        for (int Nt = 0; Nt < 4; ++Nt) acc[Mi][Nt] = Z;
      #pragma unroll
      for (int Nt = 0; Nt < 4; ++Nt) {
        const bfrag e0 = LDBACT(S.emb, 72, Nt, 0);
        const bfrag e1 = LDBACT(S.emb, 72, Nt, 1);
        #pragma unroll
        for (int Mi = 0; Mi < 3; ++Mi) {
          acc[Mi][Nt] = mfma16(wQKV[Mi][0], e0, acc[Mi][Nt]);
          acc[Mi][Nt] = mfma16(wQKV[Mi][1], e1, acc[Mi][Nt]);
        }
      }
      #pragma unroll
      for (int Mi = 0; Mi < 3; ++Mi) {
        const int oc0 = (wv + Mi * 4) * 16 + quad * 4;
        const f32x4 bb = *reinterpret_cast<const f32x4*>(&S.bin[oc0]);
        #pragma unroll
        for (int Nt = 0; Nt < 4; ++Nt) {
          const int row = Nt * 16 + m;
          uint2 u;
          u.x = pack2(acc[Mi][Nt][0] + bb[0], acc[Mi][Nt][1] + bb[1]);
          u.y = pack2(acc[Mi][Nt][2] + bb[2], acc[Mi][Nt][3] + bb[3]);
          *reinterpret_cast<uint2*>(&S.qkv[row * 200 + oc0]) = u;
        }
      }
      const int r = tid >> 2, seg = tid & 3;
      uint4 z = {0, 0, 0, 0};
      if (s < 3) {      // prefetch next sub-iter's lane inputs
        if (seg == 0) {
          const int gl = (tl0 + 16) * 4 + r;
          z.x = pack2(queue[gl], waiting[gl]);
          z.y = pack2(elapsed[tl0 + 16 + (r >> 2)], 0.f);
        }
      } else {          // stage B phase-L1 input (64 TLs, K padded to 32)
        if (seg == 0) {
          const float4 p = *reinterpret_cast<const float4*>(&phase_onehot[(n0 + r) * 4]);
          z.x = pack2(p.x, p.y);
          z.y = pack2(p.z, p.w);
          z.z = pack2(elapsed[n0 + r], 0.f);
        }
      }
      *reinterpret_cast<uint4*>(&S.xbuf[r * 32 + seg * 8]) = z;
    }
    __syncthreads();

    // ---- attention (bf16 loads, f32 math): 16 threads/TL = 4 heads x 4 queries ----
    {
      const int tl = tid >> 4, l16 = tid & 15;
      const int hh = l16 >> 2, lq = l16 & 3;
      float qf[16];
      {
        const unsigned short* qp = &S.qkv[(tl * 4 + lq) * 200 + hh * 16];
        const bfrag q0 = *reinterpret_cast<const bfrag*>(qp);
        const bfrag q1 = *reinterpret_cast<const bfrag*>(qp + 8);
        #pragma unroll
        for (int j = 0; j < 8; ++j) {
          qf[j]     = bf2f((unsigned short)q0[j]);
          qf[8 + j] = bf2f((unsigned short)q1[j]);
        }
      }
      float sc[4];
      #pragma unroll
      for (int lk = 0; lk < 4; ++lk) {
        const unsigned short* kp = &S.qkv[(tl * 4 + lk) * 200 + 64 + hh * 16];
        const bfrag k0 = *reinterpret_cast<const bfrag*>(kp);
        const bfrag k1 = *reinterpret_cast<const bfrag*>(kp + 8);
        float t = 0.f;
        #pragma unroll
        for (int j = 0; j < 8; ++j) {
          t += qf[j]     * bf2f((unsigned short)k0[j]);
          t += qf[8 + j] * bf2f((unsigned short)k1[j]);
        }
        sc[lk] = t;   // 1/sqrt(HD) folded into Q weights/bias
      }
      const float mx = fmaxf(fmaxf(sc[0], sc[1]), fmaxf(sc[2], sc[3]));
      const float e0 = __expf(sc[0] - mx), e1 = __expf(sc[1] - mx);
      const float e2 = __expf(sc[2] - mx), e3 = __expf(sc[3] - mx);
      const float inv = 1.f / (e0 + e1 + e2 + e3);
      const float pr[4] = {e0 * inv, e1 * inv, e2 * inv, e3 * inv};
      float o[16];
      #pragma unroll
      for (int j = 0; j < 16; ++j) o[j] = 0.f;
      #pragma unroll
      for (int lk = 0; lk < 4; ++lk) {
        const unsigned short* vp = &S.qkv[(tl * 4 + lk) * 200 + 128 + hh * 16];
        const bfrag v0 = *reinterpret_cast<const bfrag*>(vp);
        const bfrag v1 = *reinterpret_cast<const bfrag*>(vp + 8);
        const float p = pr[lk];
        #pragma unroll
        for (int j = 0; j < 8; ++j) {
          o[j]     += p * bf2f((unsigned short)v0[j]);
          o[8 + j] += p * bf2f((unsigned short)v1[j]);
        }
      }
      // mean over queries folded into wOUT; raw o -> om[tl][lq*64 + hh*16 + d]
      unsigned short* om = S.emb;
      const int base = tl * 264 + lq * 64 + hh * 16;
      *reinterpret_cast<uint4*>(&om[base]) =
          make_uint4(pack2(o[0], o[1]), pack2(o[2], o[3]), pack2(o[4], o[5]), pack2(o[6], o[7]));
      *reinterpret_cast<uint4*>(&om[base + 8]) =
          make_uint4(pack2(o[8], o[9]), pack2(o[10], o[11]), pack2(o[12], o[13]), pack2(o[14], o[15]));
    }
    __syncthreads();

    // ---- out-proj (K=256, mean folded): ctx^T -> LDS feat rows s*16.. ----
    {
      f32x4 acc = Z;
      #pragma unroll
      for (int kk = 0; kk < 8; ++kk)
        acc = mfma16(wOUT2[kk & 1], LDBACT(S.emb, 264, 0, kk), acc);
      const int oc0 = wv * 16 + quad * 4;
      uint2 u;
      u.x = pack2(acc[0] + S.bout[oc0],     acc[1] + S.bout[oc0 + 1]);
      u.y = pack2(acc[2] + S.bout[oc0 + 2], acc[3] + S.bout[oc0 + 3]);
      *reinterpret_cast<uint2*>(&S.feat[(s * 16 + m) * 200 + oc0]) = u;
    }
    // no barrier: next layer1 writes S.h (attn readers of qkv passed barrier);
    // feat readers are behind the post-loop barrier.
  }
  __syncthreads();

  // ================= B-part: 64 TLs =================
  // Load B-part weight fragments HERE so their live range does not overlap the
  // A-part fragments (R7 loaded everything up-front -> 42 frags live -> scratch
  // spill, 240 MB/dispatch HBM traffic). sched_barrier keeps the loads from
  // being hoisted above this point.
  __builtin_amdgcn_sched_barrier(0);
  bfrag wP1[2], wP2[2][4], wH1[2][6];
  #pragma unroll
  for (int Mi = 0; Mi < 2; ++Mi) {
    wP1[Mi] = load_wfragT(phase_w1, 128, (wv * 2 + Mi) * 16, 0, lane, 5, 1.f);
    #pragma unroll
    for (int kk = 0; kk < 4; ++kk)
      wP2[Mi][kk] = load_wfragT(phase_w2, 128, (wv * 2 + Mi) * 16, kk * 32, lane, 128, 1.f);
    #pragma unroll
    for (int kk = 0; kk < 6; ++kk)
      wH1[Mi][kk] = load_wfragT(head_w1, 128, (wv * 2 + Mi) * 16, kk * 32, lane, 192, 1.f);
  }

  // ---- phase L1 MFMA (K=32 zero-padded) -> ph ----
  {
    f32x4 acc[2][4];
    #pragma unroll
    for (int Mi = 0; Mi < 2; ++Mi)
      #pragma unroll
      for (int Nt = 0; Nt < 4; ++Nt) acc[Mi][Nt] = Z;
    #pragma unroll
    for (int Nt = 0; Nt < 4; ++Nt) {
      const bfrag b = LDBACT(S.xbuf, 32, Nt, 0);
      acc[0][Nt] = mfma16(wP1[0], b, acc[0][Nt]);
      acc[1][Nt] = mfma16(wP1[1], b, acc[1][Nt]);
    }
    #pragma unroll
    for (int Mi = 0; Mi < 2; ++Mi) {
      const int oc0 = (wv * 2 + Mi) * 16 + quad * 4;
      const f32x4 bb = *reinterpret_cast<const f32x4*>(&S.pb1[oc0]);
      #pragma unroll
      for (int Nt = 0; Nt < 4; ++Nt) {
        const int row = Nt * 16 + m;
        uint2 u;
        u.x = pack2(fmaxf(acc[Mi][Nt][0] + bb[0], 0.f), fmaxf(acc[Mi][Nt][1] + bb[1], 0.f));
        u.y = pack2(fmaxf(acc[Mi][Nt][2] + bb[2], 0.f), fmaxf(acc[Mi][Nt][3] + bb[3], 0.f));
        *reinterpret_cast<uint2*>(&S.ph[row * 136 + oc0]) = u;
      }
    }
  }
  __syncthreads();

  // ---- phase L2 (K=128) -> feat cols 64..191 ----
  {
    f32x4 acc[2][4];
    #pragma unroll
    for (int Mi = 0; Mi < 2; ++Mi)
      #pragma unroll
      for (int Nt = 0; Nt < 4; ++Nt) acc[Mi][Nt] = Z;
    #pragma unroll
    for (int kk = 0; kk < 4; ++kk)
      #pragma unroll
      for (int Nt = 0; Nt < 4; ++Nt) {
        const bfrag b = LDBACT(S.ph, 136, Nt, kk);
        acc[0][Nt] = mfma16(wP2[0][kk], b, acc[0][Nt]);
        acc[1][Nt] = mfma16(wP2[1][kk], b, acc[1][Nt]);
      }
    #pragma unroll
    for (int Mi = 0; Mi < 2; ++Mi) {
      const int oc0 = (wv * 2 + Mi) * 16 + quad * 4;
      const f32x4 bb = *reinterpret_cast<const f32x4*>(&S.pb2[oc0]);
      #pragma unroll
      for (int Nt = 0; Nt < 4; ++Nt) {
        const int row = Nt * 16 + m;
        uint2 u;
        u.x = pack2(fmaxf(acc[Mi][Nt][0] + bb[0], 0.f), fmaxf(acc[Mi][Nt][1] + bb[1], 0.f));
        u.y = pack2(fmaxf(acc[Mi][Nt][2] + bb[2], 0.f), fmaxf(acc[Mi][Nt][3] + bb[3], 0.f));
        *reinterpret_cast<uint2*>(&S.feat[row * 200 + 64 + oc0]) = u;
      }
    }
  }
  __syncthreads();

  // ---- head L1 (K=192) with per-region bias -> ph (overlay) ----
  {
    f32x4 acc[2][4];
    #pragma unroll
    for (int Mi = 0; Mi < 2; ++Mi)
      #pragma unroll
      for (int Nt = 0; Nt < 4; ++Nt) acc[Mi][Nt] = Z;
    #pragma unroll
    for (int kk = 0; kk < 6; ++kk)
      #pragma unroll
      for (int Nt = 0; Nt < 4; ++Nt) {
        const bfrag b = LDBACT(S.feat, 200, Nt, kk);
        acc[0][Nt] = mfma16(wH1[0][kk], b, acc[0][Nt]);
        acc[1][Nt] = mfma16(wH1[1][kk], b, acc[1][Nt]);
      }
    #pragma unroll
    for (int Mi = 0; Mi < 2; ++Mi) {
      const int oc0 = (wv * 2 + Mi) * 16 + quad * 4;
      #pragma unroll
      for (int Nt = 0; Nt < 4; ++Nt) {
        const int row = Nt * 16 + m;
        const f32x4 bb = *reinterpret_cast<const f32x4*>(&S.rbias[S.ridx[row]][oc0]);
        uint2 u;
        u.x = pack2(fmaxf(acc[Mi][Nt][0] + bb[0], 0.f), fmaxf(acc[Mi][Nt][1] + bb[1], 0.f));
        u.y = pack2(fmaxf(acc[Mi][Nt][2] + bb[2], 0.f), fmaxf(acc[Mi][Nt][3] + bb[3], 0.f));
        *reinterpret_cast<uint2*>(&S.ph[row * 136 + oc0]) = u;
      }
    }
  }
  __syncthreads();

  // ---- head L2 (128->1) + gaussian: 4 threads/TL ----
  {
    const int tl = tid >> 2, s4 = tid & 3;   // 64 TLs x 4 threads
    const unsigned short* hp = &S.ph[tl * 136 + s4 * 32];
    float t = 0.f;
    #pragma unroll
    for (int seg = 0; seg < 4; ++seg) {
      const bfrag hseg = *reinterpret_cast<const bfrag*>(hp + seg * 8);
      const float* w = &S.hw2[s4 * 32 + seg * 8];
      #pragma unroll
      for (int j = 0; j < 8; ++j)
        t += bf2f((unsigned short)hseg[j]) * w[j];
    }
    t += __shfl_xor(t, 1);
    t += __shfl_xor(t, 2);
    if (s4 == 0) {
      const int n = n0 + tl;
      const float means = t + S.consts[0];
      const float ls = S.consts[1];
      const float nz = noise[n];
      const float a = means + __expf(ls) * nz;
      out[n] = fminf(fmaxf(a, -1.f), 1.f);
      // (actions - means) == std*noise exactly -> log_prob independent of means
      out[N_TL + n] = -0.5f * (nz * nz + 2.f * ls + 1.8378770664093453f);
    }
  }
}

extern "C" void kernel_launch(void* const* d_in, const int* in_sizes, int n_in,
                              void* d_out, int out_size, void* d_ws, size_t ws_size,
                              hipStream_t stream) {
  const float* queue        = (const float*)d_in[0];
  const float* waiting      = (const float*)d_in[1];
  const float* phase_onehot = (const float*)d_in[2];
  const float* elapsed      = (const float*)d_in[3];
  const int*   region_ids   = (const int*)d_in[4];
  const float* noise        = (const float*)d_in[5];
  const float* lane_w1      = (const float*)d_in[6];
  const float* lane_b1      = (const float*)d_in[7];
  const float* lane_w2      = (const float*)d_in[8];
  const float* lane_b2      = (const float*)d_in[9];
  const float* attn_in_w    = (const float*)d_in[10];
  const float* attn_in_b    = (const float*)d_in[11];
  const float* attn_out_w   = (const float*)d_in[12];
  const float* attn_out_b   = (const float*)d_in[13];
  const float* phase_w1     = (const float*)d_in[14];
  const float* phase_b1     = (const float*)d_in[15];
  const float* phase_w2     = (const float*)d_in[16];
  const float* phase_b2     = (const float*)d_in[17];
  const float* region_table = (const float*)d_in[18];
  const float* head_w1      = (const float*)d_in[19];
  const float* head_b1      = (const float*)d_in[20];
  const float* head_w2      = (const float*)d_in[21];
  const float* head_b2      = (const float*)d_in[22];
  const float* log_std      = (const float*)d_in[23];

  float* out = (float*)d_out;
  (void)d_ws; (void)ws_size;

  hipLaunchKernelGGL(fused_policy, dim3(GRID), dim3(BLK), 0, stream,
                     queue, waiting, phase_onehot, elapsed, region_ids, noise,
                     lane_w1, lane_b1, lane_w2, lane_b2,
                     attn_in_w, attn_in_b, attn_out_w, attn_out_b,
                     phase_w1, phase_b1, phase_w2, phase_b2, region_table,
                     head_w1, head_b1, head_w2, head_b2, log_std, out);
}

// Round 9
// 200.482 us; speedup vs baseline: 1.5536x; 1.0391x over previous
//
#include <hip/hip_runtime.h>
#include <math.h>

#define N_TL 131072
#define GRID 2048          // 64 TLs per block, single pass
#define BLK 256

typedef __attribute__((ext_vector_type(8))) short bfrag;
typedef __attribute__((ext_vector_type(4))) float f32x4;

// RNE bf16 (weights, staged once)
__device__ __forceinline__ unsigned short f2bf_rne(float x) {
  unsigned int u = __float_as_uint(x);
  return (unsigned short)((u + 0x7fffu + ((u >> 16) & 1u)) >> 16);
}
// round-half-up pack of 2 floats -> bf16x2 via v_perm (3 VALU)
__device__ __forceinline__ unsigned int pack2(float a, float b) {
  return __builtin_amdgcn_perm(__float_as_uint(b) + 0x8000u,
                               __float_as_uint(a) + 0x8000u, 0x07060302u);
}
__device__ __forceinline__ float lo16(unsigned int u) { return __uint_as_float(u << 16); }
__device__ __forceinline__ float hi16(unsigned int u) { return __uint_as_float(u & 0xffff0000u); }
__device__ __forceinline__ f32x4 mfma16(bfrag a, bfrag b, f32x4 c) {
  return __builtin_amdgcn_mfma_f32_16x16x32_bf16(a, b, c, 0, 0, 0);
}

// Weight A-fragment (W^T): A[m=col0+(lane&15)][k=k0+quad*8+j] = W[k][col]*scale, 0 for k>=K.
__device__ __forceinline__ bfrag load_wfragT(const float* __restrict__ w, int ncols,
                                             int col0, int k0, int lane, int K, float scale) {
  const int mm = lane & 15, qq = lane >> 4;
  bfrag f;
  #pragma unroll
  for (int j = 0; j < 8; ++j) {
    const int k = k0 + qq * 8 + j;
    const float v = (k < K) ? w[(size_t)k * ncols + col0 + mm] * scale : 0.f;
    f[j] = (short)f2bf_rne(v);
  }
  return f;
}

// B-operand (activations) from row-major bf16 LDS
#define LDBACT(arr, stride, nt, kk) \
  (*reinterpret_cast<const bfrag*>(&(arr)[((nt) * 16 + m) * (stride) + (kk) * 32 + quad * 8]))

// LDS: ~70 KB -> 2 blocks/CU
struct alignas(16) SmemF {
  union {
    unsigned short qkv[64 * 200];  // qkv bf16 during A attention (25.6 KB)
    unsigned short h[64 * 136];    // layer1 out bf16 (dead before qkv write)
    unsigned short ph[64 * 136];   // B: pL1 out; head-L1 out (A-part dead)
  };
  unsigned short emb[64 * 72];     // emb; om[16][264] overlays (9.2 KB)
  unsigned short xbuf[64 * 32];    // A layer1 input / B phase-L1 input (4 KB)
  unsigned short feat[64 * 200];   // [ctx(64) | phase_emb(128)] persists A->B (25.6 KB)
  float b1[128], b2[64], bin[192], bout[64];
  float pb1[128], pb2[128];
  float rbias[4][128];             // head_b1 + region[g] @ head_w1[192:200,:]
  float hw2[128];
  float consts[2];
  int ridx[64];
};

__global__ __launch_bounds__(BLK, 2)
void fused_policy(const float* __restrict__ queue,
                  const float* __restrict__ waiting,
                  const float* __restrict__ phase_onehot,
                  const float* __restrict__ elapsed,
                  const int* __restrict__ region_ids,
                  const float* __restrict__ noise,
                  const float* __restrict__ lane_w1,
                  const float* __restrict__ lane_b1,
                  const float* __restrict__ lane_w2,
                  const float* __restrict__ lane_b2,
                  const float* __restrict__ attn_in_w,
                  const float* __restrict__ attn_in_b,
                  const float* __restrict__ attn_out_w,
                  const float* __restrict__ attn_out_b,
                  const float* __restrict__ phase_w1,
                  const float* __restrict__ phase_b1,
                  const float* __restrict__ phase_w2,
                  const float* __restrict__ phase_b2,
                  const float* __restrict__ region_table,
                  const float* __restrict__ head_w1,
                  const float* __restrict__ head_b1,
                  const float* __restrict__ head_w2,
                  const float* __restrict__ head_b2,
                  const float* __restrict__ log_std,
                  float* __restrict__ out) {
  __shared__ SmemF S;
  const int tid  = threadIdx.x;
  const int wv   = tid >> 6;
  const int lane = tid & 63;
  const int m    = lane & 15;
  const int quad = lane >> 4;
  const int n0   = blockIdx.x * 64;         // 64 TLs per block

  // ---- A-part register weight fragments (14 frags; B frags loaded AFTER A loop) ----
  bfrag wL1[2], wL2[4], wQKV[3][2], wOUT2[2];
  #pragma unroll
  for (int Mi = 0; Mi < 2; ++Mi)
    wL1[Mi] = load_wfragT(lane_w1, 128, (wv * 2 + Mi) * 16, 0, lane, 3, 1.f);
  #pragma unroll
  for (int kk = 0; kk < 4; ++kk)
    wL2[kk] = load_wfragT(lane_w2, 64, wv * 16, kk * 32, lane, 128, 1.f);
  #pragma unroll
  for (int Mi = 0; Mi < 3; ++Mi)
    #pragma unroll
    for (int kk = 0; kk < 2; ++kk)
      wQKV[Mi][kk] = load_wfragT(attn_in_w, 192, (wv + Mi * 4) * 16, kk * 32, lane, 64,
                                 Mi == 0 ? 0.25f : 1.f);   // fold 1/sqrt(HD) into Q
  // out-proj with query-mean folded: K=256, W'[k][c] = Wout[k&63][c]*0.25 -> 2 distinct frags
  #pragma unroll
  for (int kk = 0; kk < 2; ++kk) {
    bfrag f;
    #pragma unroll
    for (int j = 0; j < 8; ++j) {
      const int k = kk * 32 + quad * 8 + j;
      f[j] = (short)f2bf_rne(attn_out_w[(size_t)k * 64 + wv * 16 + m] * 0.25f);
    }
    wOUT2[kk] = f;
  }

  // ---- stage biases / constants ----
  for (int i = tid; i < 128; i += BLK) S.b1[i] = lane_b1[i];
  for (int i = tid; i < 64;  i += BLK) S.b2[i] = lane_b2[i];
  for (int i = tid; i < 192; i += BLK) S.bin[i] = attn_in_b[i] * ((i < 64) ? 0.25f : 1.f);
  for (int i = tid; i < 64;  i += BLK) S.bout[i] = attn_out_b[i];
  for (int i = tid; i < 128; i += BLK) S.pb1[i] = phase_b1[i];
  for (int i = tid; i < 128; i += BLK) S.pb2[i] = phase_b2[i];
  for (int i = tid; i < 128; i += BLK) S.hw2[i] = head_w2[i];
  for (int i = tid; i < 512; i += BLK) {
    const int g = i >> 7, c = i & 127;
    float acc = head_b1[c];
    #pragma unroll
    for (int j = 0; j < 8; ++j) acc += region_table[g * 8 + j] * head_w1[(192 + j) * 128 + c];
    S.rbias[g][c] = acc;
  }
  if (tid == 0) { S.consts[0] = head_b2[0]; S.consts[1] = log_std[0]; }
  if (tid < 64) {
    int r = region_ids[n0 + tid];
    S.ridx[tid] = r < 0 ? 0 : (r > 3 ? 3 : r);
  }
  // stage x for sub-iter 0 (16 TLs x 4 lane-rows, K padded to 32)
  {
    const int r = tid >> 2, seg = tid & 3;
    uint4 z = {0, 0, 0, 0};
    if (seg == 0) {
      const int gl = n0 * 4 + r;
      z.x = pack2(queue[gl], waiting[gl]);
      z.y = pack2(elapsed[n0 + (r >> 2)], 0.f);
    }
    *reinterpret_cast<uint4*>(&S.xbuf[r * 32 + seg * 8]) = z;
  }
  __syncthreads();

  // ================= A-part: 4 sub-iters of 16 TLs =================
  #pragma unroll 1
  for (int s = 0; s < 4; ++s) {
    const int tl0 = n0 + s * 16;

    // ---- layer1 MFMA (K=32 zero-padded): h^T = w1^T @ x, bias in acc-init ----
    {
      f32x4 acc[2][4];
      #pragma unroll
      for (int Mi = 0; Mi < 2; ++Mi) {
        const f32x4 bb = *reinterpret_cast<const f32x4*>(&S.b1[(wv * 2 + Mi) * 16 + quad * 4]);
        #pragma unroll
        for (int Nt = 0; Nt < 4; ++Nt) acc[Mi][Nt] = bb;
      }
      #pragma unroll
      for (int Nt = 0; Nt < 4; ++Nt) {
        const bfrag b = LDBACT(S.xbuf, 32, Nt, 0);
        acc[0][Nt] = mfma16(wL1[0], b, acc[0][Nt]);
        acc[1][Nt] = mfma16(wL1[1], b, acc[1][Nt]);
      }
      #pragma unroll
      for (int Mi = 0; Mi < 2; ++Mi) {
        const int oc0 = (wv * 2 + Mi) * 16 + quad * 4;
        #pragma unroll
        for (int Nt = 0; Nt < 4; ++Nt) {
          const int row = Nt * 16 + m;
          uint2 u;
          u.x = pack2(fmaxf(acc[Mi][Nt][0], 0.f), fmaxf(acc[Mi][Nt][1], 0.f));
          u.y = pack2(fmaxf(acc[Mi][Nt][2], 0.f), fmaxf(acc[Mi][Nt][3], 0.f));
          *reinterpret_cast<uint2*>(&S.h[row * 136 + oc0]) = u;
        }
      }
    }
    __syncthreads();

    // ---- layer2: emb^T = w2^T @ h, bias in acc-init ----
    {
      const int oc0 = wv * 16 + quad * 4;
      const f32x4 bb = *reinterpret_cast<const f32x4*>(&S.b2[oc0]);
      f32x4 acc[4] = {bb, bb, bb, bb};
      #pragma unroll
      for (int Nt = 0; Nt < 4; ++Nt)
        #pragma unroll
        for (int kk = 0; kk < 4; ++kk)
          acc[Nt] = mfma16(wL2[kk], LDBACT(S.h, 136, Nt, kk), acc[Nt]);
      #pragma unroll
      for (int Nt = 0; Nt < 4; ++Nt) {
        const int row = Nt * 16 + m;
        uint2 u;
        u.x = pack2(fmaxf(acc[Nt][0], 0.f), fmaxf(acc[Nt][1], 0.f));
        u.y = pack2(fmaxf(acc[Nt][2], 0.f), fmaxf(acc[Nt][3], 0.f));
        *reinterpret_cast<uint2*>(&S.emb[row * 72 + oc0]) = u;
      }
    }
    __syncthreads();

    // ---- QKV: qkv^T = Win^T @ emb (bf16 out), bias in acc-init; stage next x ----
    {
      f32x4 acc[3][4];
      #pragma unroll
      for (int Mi = 0; Mi < 3; ++Mi) {
        const f32x4 bb = *reinterpret_cast<const f32x4*>(&S.bin[(wv + Mi * 4) * 16 + quad * 4]);
        #pragma unroll
        for (int Nt = 0; Nt < 4; ++Nt) acc[Mi][Nt] = bb;
      }
      #pragma unroll
      for (int Nt = 0; Nt < 4; ++Nt) {
        const bfrag e0 = LDBACT(S.emb, 72, Nt, 0);
        const bfrag e1 = LDBACT(S.emb, 72, Nt, 1);
        #pragma unroll
        for (int Mi = 0; Mi < 3; ++Mi) {
          acc[Mi][Nt] = mfma16(wQKV[Mi][0], e0, acc[Mi][Nt]);
          acc[Mi][Nt] = mfma16(wQKV[Mi][1], e1, acc[Mi][Nt]);
        }
      }
      #pragma unroll
      for (int Mi = 0; Mi < 3; ++Mi) {
        const int oc0 = (wv + Mi * 4) * 16 + quad * 4;
        #pragma unroll
        for (int Nt = 0; Nt < 4; ++Nt) {
          const int row = Nt * 16 + m;
          uint2 u;
          u.x = pack2(acc[Mi][Nt][0], acc[Mi][Nt][1]);
          u.y = pack2(acc[Mi][Nt][2], acc[Mi][Nt][3]);
          *reinterpret_cast<uint2*>(&S.qkv[row * 200 + oc0]) = u;
        }
      }
      const int r = tid >> 2, seg = tid & 3;
      uint4 z = {0, 0, 0, 0};
      if (s < 3) {      // prefetch next sub-iter's lane inputs
        if (seg == 0) {
          const int gl = (tl0 + 16) * 4 + r;
          z.x = pack2(queue[gl], waiting[gl]);
          z.y = pack2(elapsed[tl0 + 16 + (r >> 2)], 0.f);
        }
      } else {          // stage B phase-L1 input (64 TLs, K padded to 32)
        if (seg == 0) {
          const float4 p = *reinterpret_cast<const float4*>(&phase_onehot[(n0 + r) * 4]);
          z.x = pack2(p.x, p.y);
          z.y = pack2(p.z, p.w);
          z.z = pack2(elapsed[n0 + r], 0.f);
        }
      }
      *reinterpret_cast<uint4*>(&S.xbuf[r * 32 + seg * 8]) = z;
    }
    __syncthreads();

    // ---- attention: 16 threads/TL = 4 heads x 4 queries; uint lo/hi unpack ----
    {
      const int tl = tid >> 4, l16 = tid & 15;
      const int hh = l16 >> 2, lq = l16 & 3;
      const unsigned int* qp = reinterpret_cast<const unsigned int*>(
          &S.qkv[(tl * 4 + lq) * 200 + hh * 16]);
      unsigned int qu[8];
      #pragma unroll
      for (int j = 0; j < 8; ++j) qu[j] = qp[j];
      float qlo[8], qhi[8];
      #pragma unroll
      for (int j = 0; j < 8; ++j) { qlo[j] = lo16(qu[j]); qhi[j] = hi16(qu[j]); }
      float sc[4];
      #pragma unroll
      for (int lk = 0; lk < 4; ++lk) {
        const unsigned int* kp = reinterpret_cast<const unsigned int*>(
            &S.qkv[(tl * 4 + lk) * 200 + 64 + hh * 16]);
        float tx = 0.f, ty = 0.f;
        #pragma unroll
        for (int j = 0; j < 8; ++j) {
          const unsigned int ku = kp[j];
          tx += qlo[j] * lo16(ku);
          ty += qhi[j] * hi16(ku);
        }
        sc[lk] = tx + ty;   // 1/sqrt(HD) folded into Q weights/bias
      }
      const float mx = fmaxf(fmaxf(sc[0], sc[1]), fmaxf(sc[2], sc[3]));
      const float e0 = __expf(sc[0] - mx), e1 = __expf(sc[1] - mx);
      const float e2 = __expf(sc[2] - mx), e3 = __expf(sc[3] - mx);
      const float inv = 1.f / (e0 + e1 + e2 + e3);
      const float pr[4] = {e0 * inv, e1 * inv, e2 * inv, e3 * inv};
      float olo[8], ohi[8];
      #pragma unroll
      for (int j = 0; j < 8; ++j) { olo[j] = 0.f; ohi[j] = 0.f; }
      #pragma unroll
      for (int lk = 0; lk < 4; ++lk) {
        const unsigned int* vp = reinterpret_cast<const unsigned int*>(
            &S.qkv[(tl * 4 + lk) * 200 + 128 + hh * 16]);
        const float p = pr[lk];
        #pragma unroll
        for (int j = 0; j < 8; ++j) {
          const unsigned int vu = vp[j];
          olo[j] += p * lo16(vu);
          ohi[j] += p * hi16(vu);
        }
      }
      // mean over queries folded into wOUT; raw o -> om[tl][lq*64 + hh*16 + d]
      unsigned short* om = S.emb;
      const int base = tl * 264 + lq * 64 + hh * 16;
      *reinterpret_cast<uint4*>(&om[base]) =
          make_uint4(pack2(olo[0], ohi[0]), pack2(olo[1], ohi[1]),
                     pack2(olo[2], ohi[2]), pack2(olo[3], ohi[3]));
      *reinterpret_cast<uint4*>(&om[base + 8]) =
          make_uint4(pack2(olo[4], ohi[4]), pack2(olo[5], ohi[5]),
                     pack2(olo[6], ohi[6]), pack2(olo[7], ohi[7]));
    }
    __syncthreads();

    // ---- out-proj (K=256, mean folded), bias in acc-init -> feat rows s*16.. ----
    {
      const int oc0 = wv * 16 + quad * 4;
      f32x4 acc = *reinterpret_cast<const f32x4*>(&S.bout[oc0]);
      #pragma unroll
      for (int kk = 0; kk < 8; ++kk)
        acc = mfma16(wOUT2[kk & 1], LDBACT(S.emb, 264, 0, kk), acc);
      uint2 u;
      u.x = pack2(acc[0], acc[1]);
      u.y = pack2(acc[2], acc[3]);
      *reinterpret_cast<uint2*>(&S.feat[(s * 16 + m) * 200 + oc0]) = u;
    }
    // no barrier: next layer1 writes S.h (attn readers of qkv passed barrier);
    // feat readers are behind the post-loop barrier.
  }
  __syncthreads();

  // ================= B-part: 64 TLs =================
  // B-part weight fragments loaded HERE so their live range does not overlap
  // the A-part fragments (R7's up-front load -> scratch spill).
  __builtin_amdgcn_sched_barrier(0);
  bfrag wP1[2], wP2[2][4], wH1[2][6];
  #pragma unroll
  for (int Mi = 0; Mi < 2; ++Mi) {
    wP1[Mi] = load_wfragT(phase_w1, 128, (wv * 2 + Mi) * 16, 0, lane, 5, 1.f);
    #pragma unroll
    for (int kk = 0; kk < 4; ++kk)
      wP2[Mi][kk] = load_wfragT(phase_w2, 128, (wv * 2 + Mi) * 16, kk * 32, lane, 128, 1.f);
    #pragma unroll
    for (int kk = 0; kk < 6; ++kk)
      wH1[Mi][kk] = load_wfragT(head_w1, 128, (wv * 2 + Mi) * 16, kk * 32, lane, 192, 1.f);
  }

  // ---- phase L1 MFMA (K=32 zero-padded), bias in acc-init -> ph ----
  {
    f32x4 acc[2][4];
    #pragma unroll
    for (int Mi = 0; Mi < 2; ++Mi) {
      const f32x4 bb = *reinterpret_cast<const f32x4*>(&S.pb1[(wv * 2 + Mi) * 16 + quad * 4]);
      #pragma unroll
      for (int Nt = 0; Nt < 4; ++Nt) acc[Mi][Nt] = bb;
    }
    #pragma unroll
    for (int Nt = 0; Nt < 4; ++Nt) {
      const bfrag b = LDBACT(S.xbuf, 32, Nt, 0);
      acc[0][Nt] = mfma16(wP1[0], b, acc[0][Nt]);
      acc[1][Nt] = mfma16(wP1[1], b, acc[1][Nt]);
    }
    #pragma unroll
    for (int Mi = 0; Mi < 2; ++Mi) {
      const int oc0 = (wv * 2 + Mi) * 16 + quad * 4;
      #pragma unroll
      for (int Nt = 0; Nt < 4; ++Nt) {
        const int row = Nt * 16 + m;
        uint2 u;
        u.x = pack2(fmaxf(acc[Mi][Nt][0], 0.f), fmaxf(acc[Mi][Nt][1], 0.f));
        u.y = pack2(fmaxf(acc[Mi][Nt][2], 0.f), fmaxf(acc[Mi][Nt][3], 0.f));
        *reinterpret_cast<uint2*>(&S.ph[row * 136 + oc0]) = u;
      }
    }
  }
  __syncthreads();

  // ---- phase L2 (K=128), bias in acc-init -> feat cols 64..191 ----
  {
    f32x4 acc[2][4];
    #pragma unroll
    for (int Mi = 0; Mi < 2; ++Mi) {
      const f32x4 bb = *reinterpret_cast<const f32x4*>(&S.pb2[(wv * 2 + Mi) * 16 + quad * 4]);
      #pragma unroll
      for (int Nt = 0; Nt < 4; ++Nt) acc[Mi][Nt] = bb;
    }
    #pragma unroll
    for (int kk = 0; kk < 4; ++kk)
      #pragma unroll
      for (int Nt = 0; Nt < 4; ++Nt) {
        const bfrag b = LDBACT(S.ph, 136, Nt, kk);
        acc[0][Nt] = mfma16(wP2[0][kk], b, acc[0][Nt]);
        acc[1][Nt] = mfma16(wP2[1][kk], b, acc[1][Nt]);
      }
    #pragma unroll
    for (int Mi = 0; Mi < 2; ++Mi) {
      const int oc0 = (wv * 2 + Mi) * 16 + quad * 4;
      #pragma unroll
      for (int Nt = 0; Nt < 4; ++Nt) {
        const int row = Nt * 16 + m;
        uint2 u;
        u.x = pack2(fmaxf(acc[Mi][Nt][0], 0.f), fmaxf(acc[Mi][Nt][1], 0.f));
        u.y = pack2(fmaxf(acc[Mi][Nt][2], 0.f), fmaxf(acc[Mi][Nt][3], 0.f));
        *reinterpret_cast<uint2*>(&S.feat[row * 200 + 64 + oc0]) = u;
      }
    }
  }
  __syncthreads();

  // ---- head L1 (K=192), per-region bias in acc-init -> ph (overlay) ----
  {
    f32x4 acc[2][4];
    #pragma unroll
    for (int Mi = 0; Mi < 2; ++Mi) {
      const int oc0 = (wv * 2 + Mi) * 16 + quad * 4;
      #pragma unroll
      for (int Nt = 0; Nt < 4; ++Nt)
        acc[Mi][Nt] = *reinterpret_cast<const f32x4*>(&S.rbias[S.ridx[Nt * 16 + m]][oc0]);
    }
    #pragma unroll
    for (int kk = 0; kk < 6; ++kk)
      #pragma unroll
      for (int Nt = 0; Nt < 4; ++Nt) {
        const bfrag b = LDBACT(S.feat, 200, Nt, kk);
        acc[0][Nt] = mfma16(wH1[0][kk], b, acc[0][Nt]);
        acc[1][Nt] = mfma16(wH1[1][kk], b, acc[1][Nt]);
      }
    #pragma unroll
    for (int Mi = 0; Mi < 2; ++Mi) {
      const int oc0 = (wv * 2 + Mi) * 16 + quad * 4;
      #pragma unroll
      for (int Nt = 0; Nt < 4; ++Nt) {
        const int row = Nt * 16 + m;
        uint2 u;
        u.x = pack2(fmaxf(acc[Mi][Nt][0], 0.f), fmaxf(acc[Mi][Nt][1], 0.f));
        u.y = pack2(fmaxf(acc[Mi][Nt][2], 0.f), fmaxf(acc[Mi][Nt][3], 0.f));
        *reinterpret_cast<uint2*>(&S.ph[row * 136 + oc0]) = u;
      }
    }
  }
  __syncthreads();

  // ---- head L2 (128->1) + gaussian: 4 threads/TL ----
  {
    const int tl = tid >> 2, s4 = tid & 3;   // 64 TLs x 4 threads
    const unsigned int* hp = reinterpret_cast<const unsigned int*>(&S.ph[tl * 136 + s4 * 32]);
    float t = 0.f;
    #pragma unroll
    for (int j = 0; j < 16; ++j) {
      const unsigned int hu = hp[j];
      t += lo16(hu) * S.hw2[s4 * 32 + 2 * j];
      t += hi16(hu) * S.hw2[s4 * 32 + 2 * j + 1];
    }
    t += __shfl_xor(t, 1);
    t += __shfl_xor(t, 2);
    if (s4 == 0) {
      const int n = n0 + tl;
      const float means = t + S.consts[0];
      const float ls = S.consts[1];
      const float nz = noise[n];
      const float a = means + __expf(ls) * nz;
      out[n] = fminf(fmaxf(a, -1.f), 1.f);
      // (actions - means) == std*noise exactly -> log_prob independent of means
      out[N_TL + n] = -0.5f * (nz * nz + 2.f * ls + 1.8378770664093453f);
    }
  }
}

extern "C" void kernel_launch(void* const* d_in, const int* in_sizes, int n_in,
                              void* d_out, int out_size, void* d_ws, size_t ws_size,
                              hipStream_t stream) {
  const float* queue        = (const float*)d_in[0];
  const float* waiting      = (const float*)d_in[1];
  const float* phase_onehot = (const float*)d_in[2];
  const float* elapsed      = (const float*)d_in[3];
  const int*   region_ids   = (const int*)d_in[4];
  const float* noise        = (const float*)d_in[5];
  const float* lane_w1      = (const float*)d_in[6];
  const float* lane_b1      = (const float*)d_in[7];
  const float* lane_w2      = (const float*)d_in[8];
  const float* lane_b2      = (const float*)d_in[9];
  const float* attn_in_w    = (const float*)d_in[10];
  const float* attn_in_b    = (const float*)d_in[11];
  const float* attn_out_w   = (const float*)d_in[12];
  const float* attn_out_b   = (const float*)d_in[13];
  const float* phase_w1     = (const float*)d_in[14];
  const float* phase_b1     = (const float*)d_in[15];
  const float* phase_w2     = (const float*)d_in[16];
  const float* phase_b2     = (const float*)d_in[17];
  const float* region_table = (const float*)d_in[18];
  const float* head_w1      = (const float*)d_in[19];
  const float* head_b1      = (const float*)d_in[20];
  const float* head_w2      = (const float*)d_in[21];
  const float* head_b2      = (const float*)d_in[22];
  const float* log_std      = (const float*)d_in[23];

  float* out = (float*)d_out;
  (void)d_ws; (void)ws_size;

  hipLaunchKernelGGL(fused_policy, dim3(GRID), dim3(BLK), 0, stream,
                     queue, waiting, phase_onehot, elapsed, region_ids, noise,
                     lane_w1, lane_b1, lane_w2, lane_b2,
                     attn_in_w, attn_in_b, attn_out_w, attn_out_b,
                     phase_w1, phase_b1, phase_w2, phase_b2, region_table,
                     head_w1, head_b1, head_w2, head_b2, log_std, out);
}